// Round 4
// baseline (441.052 us; speedup 1.0000x reference)
//
#include <hip/hip_runtime.h>

typedef unsigned short u16;
typedef unsigned int u32;
typedef __attribute__((ext_vector_type(8))) short bf8;
typedef __attribute__((ext_vector_type(4))) float f4;
typedef __attribute__((ext_vector_type(4))) unsigned short us4;

constexpr int B = 2;
constexpr int NQ = 1024;
constexpr int C = 2048;
constexpr int DH = 128;
constexpr int G = 4;
constexpr int CD = 512;
constexpr int LR = 24;
constexpr int HR = 72;
constexpr int INTER = 64;
constexpr int K = LR * LR;  // 576
constexpr int NKV = NQ + K; // 1600

#define MFMA16(a, b, c) __builtin_amdgcn_mfma_f32_16x16x32_bf16(a, b, c, 0, 0, 0)
#define GLDS(g, l)                                                         \
  __builtin_amdgcn_global_load_lds(                                        \
      (const __attribute__((address_space(1))) void*)(g),                  \
      (__attribute__((address_space(3))) void*)(l), 16, 0, 0)

__device__ __forceinline__ u16 f2bf1(float f) {
  u32 u = __float_as_uint(f);
  u32 r = (u + 0x7fffu + ((u >> 16) & 1u)) >> 16;
  return (u16)r;
}

// --------------------- fused fp32 -> bf16 (7 tensors) -----------------------
// y<4: write STAGED layout (64x64 pieces, subtiled for MFMA); y>=4: row-major.
// staged piece(mb,kb): elem (((fr*2+kc)*4+ks)*16+r)*8+j  <-> (row=mb*64+fr*16+r,
// col=kb*64+kc*32+ks*8+j). 8 elems (one j-group) per thread.
__global__ __launch_bounds__(256) void f2bf_k7(
    const float* __restrict__ s0, const float* __restrict__ s1,
    const float* __restrict__ s2, const float* __restrict__ s3,
    const float* __restrict__ s4, const float* __restrict__ s5,
    const float* __restrict__ s6, u16* __restrict__ d0, u16* __restrict__ d1,
    u16* __restrict__ d2, u16* __restrict__ d3, u16* __restrict__ d4,
    u16* __restrict__ d5, u16* __restrict__ d6) {
  const int y = blockIdx.y;
  const float* s;
  u16* d;
  switch (y) {
    case 0: s = s0; d = d0; break;
    case 1: s = s1; d = d1; break;
    case 2: s = s2; d = d2; break;
    case 3: s = s3; d = d3; break;
    case 4: s = s4; d = d4; break;
    case 5: s = s5; d = d5; break;
    default: s = s6; d = d6; break;
  }
  const int gi = blockIdx.x * 256 + threadIdx.x;  // 8-elem group, < 524288
  float4 v0 = ((const float4*)s)[gi * 2];
  float4 v1 = ((const float4*)s)[gi * 2 + 1];
  us4 o0, o1;
  o0.x = f2bf1(v0.x); o0.y = f2bf1(v0.y); o0.z = f2bf1(v0.z); o0.w = f2bf1(v0.w);
  o1.x = f2bf1(v1.x); o1.y = f2bf1(v1.y); o1.z = f2bf1(v1.z); o1.w = f2bf1(v1.w);
  size_t g;
  if (y < 4) {
    const int row = gi >> 8, c8 = gi & 255;
    const int kb = c8 >> 3, kc = (c8 >> 2) & 1, kss = c8 & 3;
    const int mb = row >> 6, fr = (row >> 4) & 3, rr = row & 15;
    g = (size_t)(mb * 32 + kb) * 512 + ((fr * 2 + kc) * 4 + kss) * 16 + rr;
  } else {
    g = gi;
  }
  ((us4*)d)[g * 2] = o0;
  ((us4*)d)[g * 2 + 1] = o1;
}

// ------------------ 256x256 8-phase MFMA GEMM (QKV) -------------------------
// A: hs staged [2048][2048]; W: wq/wk/wv staged. C written to qb / kg / vg.
// 8 waves (2M x 4N), per-wave 128x64 out, BK=64, 4 phases/K-tile, counted vmcnt.
#define SB()                               \
  do {                                     \
    __builtin_amdgcn_sched_barrier(0);     \
    __builtin_amdgcn_s_barrier();          \
    __builtin_amdgcn_sched_barrier(0);     \
  } while (0)
#define WVM(n) asm volatile("s_waitcnt vmcnt(" #n ")" ::: "memory")

__global__ __launch_bounds__(512, 2) void gemm256(
    const u16* __restrict__ Ast, const u16* __restrict__ Wq,
    const u16* __restrict__ Wk, const u16* __restrict__ Wv,
    u16* __restrict__ outq, u16* __restrict__ kg, u16* __restrict__ vg) {
  __shared__ u16 As[2][4][4096];
  __shared__ u16 Bs[2][4][4096];
  const int tid = threadIdx.x, lane = tid & 63, w = tid >> 6;
  const int wm = w >> 2, wn = w & 3;
  const int ks = lane >> 4, r = lane & 15;
  const int bid = blockIdx.x;  // 0..191, 192 % 8 == 0 -> simple XCD swizzle
  const int swz = (bid & 7) * 24 + (bid >> 3);
  const int mt = swz / 24, nt = swz % 24;
  const u16* Wst = (nt < 8) ? Wq : (nt < 16) ? Wk : Wv;
  const int nb0 = (nt & 7) * 4;
  const int mb0 = mt * 4;

#define ST_A03(bi, kt)                                                        \
  do {                                                                        \
    GLDS(Ast + ((size_t)(mb0 + 0) * 32 + (kt)) * 4096 + tid * 8,              \
         &As[bi][0][tid * 8]);                                                \
    GLDS(Ast + ((size_t)(mb0 + 2) * 32 + (kt)) * 4096 + tid * 8,              \
         &As[bi][2][tid * 8]);                                                \
  } while (0)
#define ST_A47(bi, kt)                                                        \
  do {                                                                        \
    GLDS(Ast + ((size_t)(mb0 + 1) * 32 + (kt)) * 4096 + tid * 8,              \
         &As[bi][1][tid * 8]);                                                \
    GLDS(Ast + ((size_t)(mb0 + 3) * 32 + (kt)) * 4096 + tid * 8,              \
         &As[bi][3][tid * 8]);                                                \
  } while (0)
#define ST_B01(bi, kt)                                                        \
  do {                                                                        \
    GLDS(Wst + ((size_t)(nb0 + 0) * 32 + (kt)) * 4096 + tid * 8,              \
         &Bs[bi][0][tid * 8]);                                                \
    GLDS(Wst + ((size_t)(nb0 + 1) * 32 + (kt)) * 4096 + tid * 8,              \
         &Bs[bi][1][tid * 8]);                                                \
  } while (0)
#define ST_B23(bi, kt)                                                        \
  do {                                                                        \
    GLDS(Wst + ((size_t)(nb0 + 2) * 32 + (kt)) * 4096 + tid * 8,              \
         &Bs[bi][2][tid * 8]);                                                \
    GLDS(Wst + ((size_t)(nb0 + 3) * 32 + (kt)) * 4096 + tid * 8,              \
         &Bs[bi][3][tid * 8]);                                                \
  } while (0)
#define RD_A(dst, bi, half, kc)                                               \
  _Pragma("unroll") for (int i2 = 0; i2 < 4; ++i2) dst[i2] =                  \
      *(const bf8*)(&As[bi][wm * 2 + (half)]                                  \
                       [((i2 * 2 + (kc)) * 4 + ks) * 128 + r * 8]);
#define RD_B(dst, bi, kc)                                                     \
  _Pragma("unroll") for (int j2 = 0; j2 < 4; ++j2) dst[j2] =                  \
      *(const bf8*)(&Bs[bi][wn][((j2 * 2 + (kc)) * 4 + ks) * 128 + r * 8]);
#define MM(ACC, AF, BF)                                                       \
  do {                                                                        \
    __builtin_amdgcn_s_setprio(1);                                            \
    _Pragma("unroll") for (int i3 = 0; i3 < 4; ++i3)                          \
        _Pragma("unroll") for (int j3 = 0; j3 < 4; ++j3) ACC[i3][j3] =        \
            MFMA16(AF[i3], BF[j3], ACC[i3][j3]);                              \
    __builtin_amdgcn_s_setprio(0);                                            \
  } while (0)

  f4 accA[4][4], accB[4][4];
#pragma unroll
  for (int i = 0; i < 4; ++i)
#pragma unroll
    for (int j = 0; j < 4; ++j) {
      accA[i][j] = f4{0.f, 0.f, 0.f, 0.f};
      accB[i][j] = f4{0.f, 0.f, 0.f, 0.f};
    }
  bf8 af[4], b0[4], b1[4];

  // prologue: tile0 fully + tile1 A03,B01 -> 12 GLDS; need first 6 complete
  ST_A03(0, 0); ST_B01(0, 0); ST_B23(0, 0); ST_A47(0, 0);
  ST_A03(1, 1); ST_B01(1, 1);
  WVM(6);
  SB();

  for (int t = 0; t < 32; ++t) {
    const int buf = t & 1;
    // ---- P1: Q(fr0-3, kc0) ----
    RD_A(af, buf, 0, 0);
    RD_B(b0, buf, 0);
    if (t + 1 < 32) ST_B23(buf ^ 1, t + 1);
    SB();
    MM(accA, af, b0);
    SB();
    // ---- P2: Q(fr0-3, kc1) ----
    RD_A(af, buf, 0, 1);
    RD_B(b1, buf, 1);
    if (t + 1 < 32) ST_A47(buf ^ 1, t + 1);
    SB();
    MM(accA, af, b1);
    if (t + 1 < 32) { WVM(8); } else { WVM(0); }
    SB();
    // ---- P3: Q(fr4-7, kc0) ----
    RD_A(af, buf, 1, 0);
    if (t + 2 < 32) ST_A03(buf, t + 2);
    SB();
    MM(accB, af, b0);
    SB();
    // ---- P4: Q(fr4-7, kc1) ----
    RD_A(af, buf, 1, 1);
    if (t + 2 < 32) ST_B01(buf, t + 2);
    SB();
    MM(accB, af, b1);
    if (t + 2 < 32) { WVM(6); } else if (t + 1 < 32) { WVM(2); }
    SB();
  }

  // ---- epilogue: route to qb / kg / vg (same mapping as before) ----
#define EPI(ACC, HALF)                                                        \
  _Pragma("unroll") for (int i = 0; i < 4; ++i)                               \
      _Pragma("unroll") for (int j = 0; j < 4; ++j)                           \
          _Pragma("unroll") for (int rr = 0; rr < 4; ++rr) {                  \
    const int m = mt * 256 + wm * 128 + (HALF)*64 + i * 16 + ks * 4 + rr;     \
    const int n = nt * 256 + wn * 64 + j * 16 + r;                            \
    const float v = ACC[i][j][rr];                                            \
    const int sel = n >> 11, nn = n & 2047, hh = nn >> 7, dd = nn & 127;      \
    const int bb = m >> 10, qq = m & 1023;                                    \
    const u16 bv = f2bf1(v);                                                  \
    if (sel == 0) {                                                           \
      outq[(size_t)m * 2048 + nn] = bv;                                       \
    } else if (sel == 1) {                                                    \
      kg[(((size_t)(bb * 16 + hh) * 50 + (qq >> 5)) * 16 + (dd >> 3)) * 256 + \
         (qq & 31) * 8 + (dd & 7)] = bv;                                      \
    } else {                                                                  \
      vg[((size_t)(bb * 16 + hh) * 200 + (qq >> 3)) * 1024 + dd * 8 +         \
         (qq & 7)] = bv;                                                      \
    }                                                                         \
  }
  EPI(accA, 0)
  EPI(accB, 1)
#undef EPI
}

// ----------------- bf16 MFMA GEMM (m97, modes 1/2 only) ---------------------
template <int MODE>
__global__ __launch_bounds__(256) void gemm_mf(
    const u16* __restrict__ A, const u16* __restrict__ W0,
    const u16* __restrict__ W1, const float* __restrict__ bias0,
    const float* __restrict__ bias1, u16* __restrict__ kg,
    u16* __restrict__ vg, float* __restrict__ outf) {
  __shared__ u16 As2[2][4096];
  __shared__ u16 Ws2[2][4096];
  const int tid = threadIdx.x, lane = tid & 63, w = tid >> 6;
  const int wr = w >> 1, wc = w & 1;
  const int m0 = blockIdx.y * 128, nb = blockIdx.x;
  const u16* Wp;
  if (MODE == 1) Wp = (nb < 16) ? W0 : W1;
  else Wp = W0;
  const int n0l = (MODE == 2 ? nb : (nb & 15)) * 128;
  f4 acc[4][4];
#pragma unroll
  for (int i = 0; i < 4; ++i)
#pragma unroll
    for (int j = 0; j < 4; ++j) acc[i][j] = f4{0.f, 0.f, 0.f, 0.f};
  const int srow = lane >> 2, scol = (lane & 3) * 8;
  const int ch0 = w * 2;
  const u16* Ab = A + (size_t)m0 * 2048 + scol;
  const u16* Wb = Wp + (size_t)n0l * 2048 + scol;
  const int koff = (lane >> 4) * 8;
  const int arow = wr * 64 + (lane & 15), brow = wc * 64 + (lane & 15);

#define GSTAGE(bi, k0)                                                        \
  do {                                                                        \
    _Pragma("unroll") for (int c = 0; c < 2; ++c) {                           \
      const int chunk = ch0 + c;                                              \
      const int row = chunk * 16 + srow;                                      \
      GLDS(Ab + (size_t)row * 2048 + (k0), &As2[bi][chunk * 512 + lane * 8]); \
      GLDS(Wb + (size_t)row * 2048 + (k0), &Ws2[bi][chunk * 512 + lane * 8]); \
    }                                                                         \
  } while (0)

  GSTAGE(0, 0);
  int cur = 0;
  for (int k0 = 0; k0 < 2048; k0 += 32) {
    __syncthreads();
    if (k0 + 32 < 2048) GSTAGE(cur ^ 1, k0 + 32);
    bf8 af2[4], bw[4];
#pragma unroll
    for (int i = 0; i < 4; ++i)
      af2[i] = *(const bf8*)(&As2[cur][(arow + i * 16) * 32 + koff]);
#pragma unroll
    for (int j = 0; j < 4; ++j)
      bw[j] = *(const bf8*)(&Ws2[cur][(brow + j * 16) * 32 + koff]);
#pragma unroll
    for (int i = 0; i < 4; ++i)
#pragma unroll
      for (int j = 0; j < 4; ++j)
        acc[i][j] = MFMA16(af2[i], bw[j], acc[i][j]);
    cur ^= 1;
  }
#undef GSTAGE
  const int rbase = (lane >> 4) * 4;
  const int cql = lane & 15;
#pragma unroll
  for (int i = 0; i < 4; ++i) {
#pragma unroll
    for (int j = 0; j < 4; ++j) {
      const int n = nb * 128 + wc * 64 + j * 16 + cql;
#pragma unroll
      for (int rr = 0; rr < 4; ++rr) {
        const int m = m0 + wr * 64 + i * 16 + rbase + rr;
        float v = acc[i][j][rr];
        if (MODE == 1) {
          const int sel = n >> 11, nn = n & 2047, hh = nn >> 7, dd = nn & 127;
          const int bb = m / 576;
          const int kv = 1024 + (m - bb * 576);
          v += (sel == 0) ? bias0[nn] : bias1[nn];
          const u16 bv = f2bf1(v);
          if (sel == 0) {
            kg[(((size_t)(bb * 16 + hh) * 50 + (kv >> 5)) * 16 + (dd >> 3)) * 256 +
               (kv & 31) * 8 + (dd & 7)] = bv;
          } else {
            vg[((size_t)(bb * 16 + hh) * 200 + (kv >> 3)) * 1024 + dd * 8 +
               (kv & 7)] = bv;
          }
        } else {
          outf[(size_t)m * 2048 + n] = v;
        }
      }
    }
  }
}

// ----------------------- offset network (tiny kernels) ----------------------
__global__ __launch_bounds__(256) void build_lr(const float* __restrict__ hs,
                                                float* __restrict__ lr) {
  int idx = blockIdx.x * 256 + threadIdx.x;
  if (idx >= B * G * CD * K) return;
  int p = idx % K;
  int c = (idx / K) % CD;
  int n = idx / (K * CD);
  int b = n >> 2, g = n & 3;
  lr[idx] = hs[((size_t)b * NQ + p) * C + g * CD + c];
}

__global__ __launch_bounds__(256) void pool_lr(const float* __restrict__ lr,
                                               float* __restrict__ pooled) {
  int row = (blockIdx.x * 256 + threadIdx.x) >> 6;
  int lane = threadIdx.x & 63;
  if (row >= B * G * CD) return;
  const float* p = lr + (size_t)row * K;
  float s = 0.f;
  for (int i = lane; i < K; i += 64) s += p[i];
  for (int o = 32; o; o >>= 1) s += __shfl_xor(s, o);
  if (lane == 0) pooled[row] = s * (1.f / K);
}

__global__ __launch_bounds__(256) void dwconv_silu(const float* __restrict__ lr,
                                                   const float* __restrict__ w,
                                                   float* __restrict__ x1) {
  int idx = blockIdx.x * 256 + threadIdx.x;
  if (idx >= B * G * CD * K) return;
  int p = idx % K;
  int c = (idx / K) % CD;
  int n = idx / (K * CD);
  int y = p / LR, x = p % LR;
  const float* wp = w + c * 9;
  const float* src = lr + ((size_t)n * CD + c) * K;
  float s = 0.f;
#pragma unroll
  for (int dy = -1; dy <= 1; ++dy)
#pragma unroll
    for (int dx = -1; dx <= 1; ++dx) {
      int yy = y + dy, xx = x + dx;
      if (yy < 0 || yy >= LR || xx < 0 || xx >= LR) continue;
      s += src[yy * LR + xx] * wp[(dy + 1) * 3 + dx + 1];
    }
  x1[idx] = s / (1.f + expf(-s));
}

__global__ __launch_bounds__(256) void ln_c512(float* __restrict__ x,
                                               const float* __restrict__ w,
                                               const float* __restrict__ b) {
  const int n = blockIdx.x / 9;
  const int p0 = (blockIdx.x % 9) * 64;
  const int pl = threadIdx.x & 63;
  const int cg = threadIdx.x >> 6;
  float* base = x + (size_t)n * CD * K + p0 + pl;
  float s = 0.f, ss = 0.f;
  for (int c = cg * 128; c < cg * 128 + 128; ++c) {
    float v = base[(size_t)c * K];
    s += v; ss += v * v;
  }
  __shared__ float rs[4][64], rss[4][64];
  rs[cg][pl] = s; rss[cg][pl] = ss;
  __syncthreads();
  float S = rs[0][pl] + rs[1][pl] + rs[2][pl] + rs[3][pl];
  float SS = rss[0][pl] + rss[1][pl] + rss[2][pl] + rss[3][pl];
  const float mean = S * (1.f / CD);
  const float inv = rsqrtf(SS * (1.f / CD) - mean * mean + 1e-5f);
  for (int c = cg * 128; c < cg * 128 + 128; ++c) {
    float v = base[(size_t)c * K];
    base[(size_t)c * K] = (v - mean) * inv * w[c] + b[c];
  }
}

__global__ __launch_bounds__(576) void proj64(const float* __restrict__ x1,
                                              const float* __restrict__ w,
                                              float* __restrict__ x2) {
  const int n = blockIdx.x >> 3;
  const int o0 = (blockIdx.x & 7) * 8;
  const int p = threadIdx.x;
  const float* xb = x1 + (size_t)n * CD * K + p;
  float acc[8] = {0.f, 0.f, 0.f, 0.f, 0.f, 0.f, 0.f, 0.f};
  for (int c = 0; c < CD; ++c) {
    float v = xb[(size_t)c * K];
#pragma unroll
    for (int j = 0; j < 8; ++j) acc[j] += v * w[(o0 + j) * CD + c];
  }
#pragma unroll
  for (int j = 0; j < 8; ++j)
    x2[((size_t)n * INTER + o0 + j) * K + p] = acc[j];
}

__global__ __launch_bounds__(64) void gate_k(const float* __restrict__ pooled,
                                             const float* __restrict__ w,
                                             const float* __restrict__ bias,
                                             float* __restrict__ gate) {
  int idx = blockIdx.x * 64 + threadIdx.x;
  if (idx >= B * G * INTER) return;
  int n = idx >> 6, o = idx & 63;
  const float* pb = pooled + n * CD;
  const float* wb = w + o * CD;
  float s = bias[o];
  for (int c = 0; c < CD; ++c) s += pb[c] * wb[c];
  gate[idx] = 1.f / (1.f + expf(-s));
}

__global__ __launch_bounds__(256) void ln2_off_pos(
    const float* __restrict__ x2, const float* __restrict__ gate,
    const float* __restrict__ ln2w, const float* __restrict__ ln2b,
    const float* __restrict__ offw, float* __restrict__ pos) {
  int wid = (blockIdx.x * 256 + threadIdx.x) >> 6;
  int lane = threadIdx.x & 63;
  if (wid >= B * G * K) return;
  int n = wid / K, p = wid % K;
  float v = x2[((size_t)n * INTER + lane) * K + p] * gate[n * INTER + lane];
  float s = v, ss = v * v;
  for (int o = 32; o; o >>= 1) {
    s += __shfl_xor(s, o);
    ss += __shfl_xor(ss, o);
  }
  float mean = s * (1.f / INTER);
  float var = ss * (1.f / INTER) - mean * mean;
  float xn = (v - mean) * rsqrtf(var + 1e-5f) * ln2w[lane] + ln2b[lane];
  float ox = xn * offw[lane];
  float oy = xn * offw[INTER + lane];
  for (int o = 32; o; o >>= 1) {
    ox += __shfl_xor(ox, o);
    oy += __shfl_xor(oy, o);
  }
  if (lane == 0) {
    int yi = p / LR, xi = p % LR;
    float rx = (xi + 0.5f) / 23.f * 2.f - 1.f;
    float ry = (yi + 0.5f) / 23.f * 2.f - 1.f;
    pos[((size_t)n * K + p) * 2 + 0] = tanhf(rx + ox);
    pos[((size_t)n * K + p) * 2 + 1] = tanhf(ry + oy);
  }
}

__global__ __launch_bounds__(256) void sample_k(const float* __restrict__ img,
                                                const float* __restrict__ pos,
                                                u16* __restrict__ samp) {
  const int bk = blockIdx.x;
  const int b = bk / K, k = bk % K;
  __shared__ int s_idx[G][4];
  __shared__ float s_w[G][4];
  if (threadIdx.x < G) {
    int g = threadIdx.x;
    int n = b * G + g;
    float px = pos[((size_t)n * K + k) * 2 + 0];
    float py = pos[((size_t)n * K + k) * 2 + 1];
    float x = (px + 1.f) * 0.5f * (HR - 1);
    float y = (py + 1.f) * 0.5f * (HR - 1);
    float x0f = floorf(x), y0f = floorf(y);
    float wx = x - x0f, wy = y - y0f;
    int x0 = min(max((int)x0f, 0), HR - 1);
    int x1 = min(x0 + 1, HR - 1);
    int y0 = min(max((int)y0f, 0), HR - 1);
    int y1 = min(y0 + 1, HR - 1);
    s_idx[g][0] = y0 * HR + x0;
    s_idx[g][1] = y0 * HR + x1;
    s_idx[g][2] = y1 * HR + x0;
    s_idx[g][3] = y1 * HR + x1;
    s_w[g][0] = (1.f - wx) * (1.f - wy);
    s_w[g][1] = wx * (1.f - wy);
    s_w[g][2] = (1.f - wx) * wy;
    s_w[g][3] = wx * wy;
  }
  __syncthreads();
  const float* ib = img + (size_t)b * HR * HR * C;
  u16* ob = samp + ((size_t)b * K + k) * C;
  for (int ch = threadIdx.x; ch < C; ch += 256) {
    int g = ch >> 9;
    float v = s_w[g][0] * ib[(size_t)s_idx[g][0] * C + ch] +
              s_w[g][1] * ib[(size_t)s_idx[g][1] * C + ch] +
              s_w[g][2] * ib[(size_t)s_idx[g][2] * C + ch] +
              s_w[g][3] * ib[(size_t)s_idx[g][3] * C + ch];
    ob[ch] = f2bf1(v);
  }
}

// ------------------ MFMA flash attention (2-phase dbuf) ---------------------
__global__ __launch_bounds__(256) void attn_mfma(
    const u16* __restrict__ qb, const u16* __restrict__ kg,
    const u16* __restrict__ vg, u16* __restrict__ aob) {
  const int i = blockIdx.x;
  const int pair = i & 255, half = i >> 8;
  const int bh = pair & 31;
  const int q8 = pair >> 5;
  const int qblk = half ? (15 - q8) : q8;
  const int b = bh >> 4, h = bh & 15;
  const int q0 = qblk * 64;
  const int tid = threadIdx.x, lane = tid & 63, w = tid >> 6;
  const int qw = q0 + w * 16;
  const int col = lane & 15, kpart = lane >> 4, rbase = kpart * 4;
  __shared__ u16 Ks[2][4096];
  __shared__ u16 Vs[2][4096];
  __shared__ u16 Pl[4][16 * 72];
  bf8 qf[4];
  {
    const u16* qp =
        qb + (size_t)(b * 1024 + qw + col) * 2048 + h * 128 + kpart * 8;
#pragma unroll
    for (int dc = 0; dc < 4; ++dc) qf[dc] = *(const bf8*)(qp + dc * 32);
  }
  f4 o[8];
#pragma unroll
  for (int df = 0; df < 8; ++df) o[df] = f4{0.f, 0.f, 0.f, 0.f};
  float m_r[4] = {-1e30f, -1e30f, -1e30f, -1e30f};
  float l_r[4] = {0.f, 0.f, 0.f, 0.f};
  const float scale = 0.08838834764831845f;
  const int nt_text = (q0 + 64) >> 5;
  const int n_tiles = nt_text + 18;
  const u16* kbh = kg + (size_t)bh * (NKV * 128);
  const u16* vbh = vg + (size_t)bh * (NKV * 128);
  u16* pw = &Pl[w][0];

#define ASTAGE(bi, kv0)                                                       \
  do {                                                                        \
    const u16* gk = kbh + (size_t)((kv0) >> 5) * 4096 + w * 1024 + lane * 8;  \
    GLDS(gk, &Ks[bi][w * 1024 + lane * 8]);                                   \
    GLDS(gk + 512, &Ks[bi][w * 1024 + 512 + lane * 8]);                       \
    const u16* gv = vbh + (size_t)((kv0) >> 3) * 1024 + w * 1024 + lane * 8;  \
    GLDS(gv, &Vs[bi][w * 1024 + lane * 8]);                                   \
    GLDS(gv + 512, &Vs[bi][w * 1024 + 512 + lane * 8]);                       \
  } while (0)

  ASTAGE(0, 0);
  int cur = 0;
  for (int t = 0; t < n_tiles; ++t) {
    const bool is_text = t < nt_text;
    const int kv0 = is_text ? (t << 5) : (1024 + ((t - nt_text) << 5));
    __syncthreads();
    if (t + 1 < n_tiles) {
      const int t1 = t + 1;
      const int kv1 =
          (t1 < nt_text) ? (t1 << 5) : (1024 + ((t1 - nt_text) << 5));
      ASTAGE(cur ^ 1, kv1);
    }
    const u16* ksb = &Ks[cur][0];
    const u16* vsb = &Vs[cur][0];
    f4 s0 = {0.f, 0.f, 0.f, 0.f}, s1 = {0.f, 0.f, 0.f, 0.f};
    __builtin_amdgcn_s_setprio(1);
#pragma unroll
    for (int dc = 0; dc < 4; ++dc) {
      const int dblk = dc * 4 + kpart;
      bf8 k0f = *(const bf8*)(ksb + (dblk * 32 + col) * 8);
      bf8 k1f = *(const bf8*)(ksb + (dblk * 32 + 16 + col) * 8);
      s0 = MFMA16(qf[dc], k0f, s0);
      s1 = MFMA16(qf[dc], k1f, s1);
    }
    __builtin_amdgcn_s_setprio(0);
    float sa[4], sc[4], mxr[4], p0[4], p1[4];
    bool grow = false;
#pragma unroll
    for (int rr = 0; rr < 4; ++rr) {
      float a = s0[rr] * scale, c2 = s1[rr] * scale;
      if (is_text) {
        const int qg = qw + rbase + rr;
        if (kv0 + col > qg) a = -1e30f;
        if (kv0 + 16 + col > qg) c2 = -1e30f;
      }
      sa[rr] = a; sc[rr] = c2;
      float mx = fmaxf(a, c2);
      mx = fmaxf(mx, __shfl_xor(mx, 1));
      mx = fmaxf(mx, __shfl_xor(mx, 2));
      mx = fmaxf(mx, __shfl_xor(mx, 4));
      mx = fmaxf(mx, __shfl_xor(mx, 8));
      mxr[rr] = mx;
      grow |= (mx > m_r[rr] + 8.f);
    }
    if (__any(grow)) {
      float fr[4];
#pragma unroll
      for (int rr = 0; rr < 4; ++rr) {
        const float mn = fmaxf(m_r[rr], mxr[rr]);
        fr[rr] = __expf(m_r[rr] - mn);
        m_r[rr] = mn;
        p0[rr] = __expf(sa[rr] - mn);
        p1[rr] = __expf(sc[rr] - mn);
        float ps = p0[rr] + p1[rr];
        ps += __shfl_xor(ps, 1);
        ps += __shfl_xor(ps, 2);
        ps += __shfl_xor(ps, 4);
        ps += __shfl_xor(ps, 8);
        l_r[rr] = l_r[rr] * fr[rr] + ps;
      }
#pragma unroll
      for (int df = 0; df < 8; ++df) {
        o[df][0] *= fr[0]; o[df][1] *= fr[1];
        o[df][2] *= fr[2]; o[df][3] *= fr[3];
      }
    } else {
#pragma unroll
      for (int rr = 0; rr < 4; ++rr) {
        p0[rr] = __expf(sa[rr] - m_r[rr]);
        p1[rr] = __expf(sc[rr] - m_r[rr]);
        float ps = p0[rr] + p1[rr];
        ps += __shfl_xor(ps, 1);
        ps += __shfl_xor(ps, 2);
        ps += __shfl_xor(ps, 4);
        ps += __shfl_xor(ps, 8);
        l_r[rr] += ps;
      }
    }
#pragma unroll
    for (int rr = 0; rr < 4; ++rr) {
      pw[(rbase + rr) * 72 + col] = f2bf1(p0[rr]);
      pw[(rbase + rr) * 72 + 16 + col] = f2bf1(p1[rr]);
    }
    bf8 pa = *(const bf8*)(pw + col * 72 + kpart * 8);
    __builtin_amdgcn_s_setprio(1);
#pragma unroll
    for (int df = 0; df < 8; ++df) {
      bf8 vf = *(const bf8*)(vsb + (kpart * 128 + df * 16 + col) * 8);
      o[df] = MFMA16(pa, vf, o[df]);
    }
    __builtin_amdgcn_s_setprio(0);
    cur ^= 1;
  }
#undef ASTAGE
  float inv[4];
#pragma unroll
  for (int rr = 0; rr < 4; ++rr) inv[rr] = 1.f / l_r[rr];
  u16* ob = aob + (size_t)(b * 1024 + qw + rbase) * 2048 + h * 128 + col;
#pragma unroll
  for (int df = 0; df < 8; ++df)
#pragma unroll
    for (int rr = 0; rr < 4; ++rr)
      ob[(size_t)rr * 2048 + df * 16] = f2bf1(o[df][rr] * inv[rr]);
}

// ---------------------------------------------------------------------------
extern "C" void kernel_launch(void* const* d_in, const int* in_sizes, int n_in,
                              void* d_out, int out_size, void* d_ws,
                              size_t ws_size, hipStream_t stream) {
  const float* hs = (const float*)d_in[0];
  const float* img = (const float*)d_in[1];
  const float* wq = (const float*)d_in[2];
  const float* wk = (const float*)d_in[3];
  const float* wv = (const float*)d_in[4];
  const float* wo = (const float*)d_in[5];
  const float* cdw = (const float*)d_in[6];
  const float* ln1w = (const float*)d_in[7];
  const float* ln1b = (const float*)d_in[8];
  const float* plrw = (const float*)d_in[9];
  const float* piw = (const float*)d_in[10];
  const float* pib = (const float*)d_in[11];
  const float* ln2w = (const float*)d_in[12];
  const float* ln2b = (const float*)d_in[13];
  const float* offw = (const float*)d_in[14];
  const float* khw = (const float*)d_in[15];
  const float* khb = (const float*)d_in[16];
  const float* vhw = (const float*)d_in[17];
  const float* vhb = (const float*)d_in[18];
  float* outp = (float*)d_out;

  u16* wsp = (u16*)d_ws;
  const size_t SZ = 4194304;  // 2048*2048
  u16* hs_st = wsp;            // staged
  u16* wq_st = wsp + SZ;       // staged; reused as aob_bf after gemm256
  u16* wk_st = wsp + 2 * SZ;   // staged
  u16* wv_st = wsp + 3 * SZ;   // staged
  u16* wo_bf = wsp + 4 * SZ;   // row-major
  u16* khw_bf = wsp + 5 * SZ;  // row-major
  u16* vhw_bf = wsp + 6 * SZ;  // row-major
  u16* qb_bf = wsp + 7 * SZ;
  u16* samp_bf = wsp + 8 * SZ;       // 1152*2048 row-major
  u16* kg = wsp + 8 * SZ + 2359296;  // 2*16*1600*128
  u16* vg = kg + 6553600;
  float* lrb = (float*)kg;  // fp32 scratch overlaps kg/vg (dead before gemms)
  float* x1b = lrb + 2359296;
  float* x2b = x1b + 2359296;
  float* poolb = x2b + 294912;
  float* gb = poolb + 4096;
  float* posb = (float*)(vg + 6553600);
  u16* aob_bf = wq_st;

  dim3 blk(256);
  // ---- offset network ----
  build_lr<<<dim3((B * G * CD * K) / 256), blk, 0, stream>>>(hs, lrb);
  pool_lr<<<dim3((B * G * CD) / 4), blk, 0, stream>>>(lrb, poolb);
  dwconv_silu<<<dim3((B * G * CD * K) / 256), blk, 0, stream>>>(lrb, cdw, x1b);
  ln_c512<<<dim3(B * G * 9), blk, 0, stream>>>(x1b, ln1w, ln1b);
  proj64<<<dim3(B * G * 8), dim3(576), 0, stream>>>(x1b, plrw, x2b);
  gate_k<<<dim3((B * G * INTER) / 64), dim3(64), 0, stream>>>(poolb, piw, pib,
                                                              gb);
  ln2_off_pos<<<dim3((B * G * K) / 4), blk, 0, stream>>>(x2b, gb, ln2w, ln2b,
                                                         offw, posb);
  sample_k<<<dim3(B * K), blk, 0, stream>>>(img, posb, samp_bf);

  // ---- bf16 conversions (fused; 0-3 staged, 4-6 row-major) ----
  f2bf_k7<<<dim3(SZ / 8 / 256, 7), blk, 0, stream>>>(
      hs, wq, wk, wv, wo, khw, vhw, hs_st, wq_st, wk_st, wv_st, wo_bf, khw_bf,
      vhw_bf);

  // ---- MFMA GEMMs ----
  gemm256<<<dim3(192), dim3(512), 0, stream>>>(hs_st, wq_st, wk_st, wv_st,
                                               qb_bf, kg, vg);
  gemm_mf<1><<<dim3(32, 9), blk, 0, stream>>>(samp_bf, khw_bf, vhw_bf, khb,
                                              vhb, kg, vg, nullptr);
  // ---- attention ----
  attn_mfma<<<dim3(512), blk, 0, stream>>>(qb_bf, kg, vg, aob_bf);
  // ---- output projection ----
  gemm_mf<2><<<dim3(16, 16), blk, 0, stream>>>(aob_bf, wo_bf, nullptr, nullptr,
                                               nullptr, nullptr, nullptr,
                                               outp);
}

// Round 5
// 421.114 us; speedup vs baseline: 1.0473x; 1.0473x over previous
//
#include <hip/hip_runtime.h>

typedef unsigned short u16;
typedef unsigned int u32;
typedef __attribute__((ext_vector_type(8))) short bf8;
typedef __attribute__((ext_vector_type(4))) float f4;
typedef __attribute__((ext_vector_type(4))) unsigned short us4;

constexpr int B = 2;
constexpr int NQ = 1024;
constexpr int C = 2048;
constexpr int DH = 128;
constexpr int G = 4;
constexpr int CD = 512;
constexpr int LR = 24;
constexpr int HR = 72;
constexpr int INTER = 64;
constexpr int K = LR * LR;  // 576
constexpr int NKV = NQ + K; // 1600

#define MFMA16(a, b, c) __builtin_amdgcn_mfma_f32_16x16x32_bf16(a, b, c, 0, 0, 0)
#define GLDS(g, l)                                                         \
  __builtin_amdgcn_global_load_lds(                                        \
      (const __attribute__((address_space(1))) void*)(g),                  \
      (__attribute__((address_space(3))) void*)(l), 16, 0, 0)

__device__ __forceinline__ u16 f2bf1(float f) {
  u32 u = __float_as_uint(f);
  u32 r = (u + 0x7fffu + ((u >> 16) & 1u)) >> 16;
  return (u16)r;
}

// --------------------- fused fp32 -> bf16 (7 tensors) -----------------------
// y<4: STAGED layout via LDS transpose — reads AND writes coalesced.
// staged piece(mb,kb) elem (((fr*2+kc)*4+ks)*16+r)*8+j <->
//   (row=mb*64+fr*16+r, col=kb*64+kc*32+ks*8+j). y>=4: row-major.
__global__ __launch_bounds__(256) void f2bf_k7(
    const float* __restrict__ s0, const float* __restrict__ s1,
    const float* __restrict__ s2, const float* __restrict__ s3,
    const float* __restrict__ s4, const float* __restrict__ s5,
    const float* __restrict__ s6, u16* __restrict__ d0, u16* __restrict__ d1,
    u16* __restrict__ d2, u16* __restrict__ d3, u16* __restrict__ d4,
    u16* __restrict__ d5, u16* __restrict__ d6) {
  __shared__ u16 L[64][68];
  const int y = blockIdx.y;
  const float* s;
  u16* d;
  switch (y) {
    case 0: s = s0; d = d0; break;
    case 1: s = s1; d = d1; break;
    case 2: s = s2; d = d2; break;
    case 3: s = s3; d = d3; break;
    case 4: s = s4; d = d4; break;
    case 5: s = s5; d = d5; break;
    default: s = s6; d = d6; break;
  }
  const int t = threadIdx.x;
  if (y < 4) {
    const int pc = blockIdx.x;  // piece 0..1023
    const int mb = pc >> 5, kb = pc & 31;
    const int rin = t >> 2, c0 = (t & 3) * 16;
    const float* src = s + (size_t)(mb * 64 + rin) * 2048 + kb * 64 + c0;
#pragma unroll
    for (int j = 0; j < 16; j += 4) {
      float4 v = *(const float4*)(src + j);
      L[rin][c0 + j] = f2bf1(v.x);
      L[rin][c0 + j + 1] = f2bf1(v.y);
      L[rin][c0 + j + 2] = f2bf1(v.z);
      L[rin][c0 + j + 3] = f2bf1(v.w);
    }
    __syncthreads();
    u16* dst = d + (size_t)pc * 4096 + t * 16;
#pragma unroll
    for (int gg = 0; gg < 2; ++gg) {
      const int g = t * 2 + gg;
      const int rh = g & 15, ks2 = (g >> 4) & 3, kc = (g >> 6) & 1, fr = g >> 7;
      const int row = fr * 16 + rh, cc = kc * 32 + ks2 * 8;
      us4 o0, o1;
      o0.x = L[row][cc];     o0.y = L[row][cc + 1];
      o0.z = L[row][cc + 2]; o0.w = L[row][cc + 3];
      o1.x = L[row][cc + 4]; o1.y = L[row][cc + 5];
      o1.z = L[row][cc + 6]; o1.w = L[row][cc + 7];
      *(us4*)(dst + gg * 8) = o0;
      *(us4*)(dst + gg * 8 + 4) = o1;
    }
  } else {
    const size_t i0 = ((size_t)blockIdx.x * 256 + t) * 16;
#pragma unroll
    for (int j = 0; j < 16; j += 4) {
      float4 v = *(const float4*)(s + i0 + j);
      us4 o;
      o.x = f2bf1(v.x); o.y = f2bf1(v.y); o.z = f2bf1(v.z); o.w = f2bf1(v.w);
      *(us4*)(d + i0 + j) = o;
    }
  }
}

// ------------------ 256x256 8-phase MFMA GEMM (QKV) -------------------------
#define SB()                               \
  do {                                     \
    __builtin_amdgcn_sched_barrier(0);     \
    __builtin_amdgcn_s_barrier();          \
    __builtin_amdgcn_sched_barrier(0);     \
  } while (0)
#define WVM(n) asm volatile("s_waitcnt vmcnt(" #n ")" ::: "memory")

__global__ __launch_bounds__(512, 2) void gemm256(
    const u16* __restrict__ Ast, const u16* __restrict__ Wq,
    const u16* __restrict__ Wk, const u16* __restrict__ Wv,
    u16* __restrict__ outq, u16* __restrict__ kg, u16* __restrict__ vg) {
  __shared__ u16 As[2][4][4096];
  __shared__ u16 Bs[2][4][4096];
  const int tid = threadIdx.x, lane = tid & 63, w = tid >> 6;
  const int wm = w >> 2, wn = w & 3;
  const int ks = lane >> 4, r = lane & 15;
  const int bid = blockIdx.x;  // 0..191
  const int swz = (bid & 7) * 24 + (bid >> 3);
  const int mt = swz / 24, nt = swz % 24;
  const u16* Wst = (nt < 8) ? Wq : (nt < 16) ? Wk : Wv;
  const int nb0 = (nt & 7) * 4;
  const int mb0 = mt * 4;

#define ST_A03(bi, kt)                                                        \
  do {                                                                        \
    GLDS(Ast + ((size_t)(mb0 + 0) * 32 + (kt)) * 4096 + tid * 8,              \
         &As[bi][0][tid * 8]);                                                \
    GLDS(Ast + ((size_t)(mb0 + 2) * 32 + (kt)) * 4096 + tid * 8,              \
         &As[bi][2][tid * 8]);                                                \
  } while (0)
#define ST_A47(bi, kt)                                                        \
  do {                                                                        \
    GLDS(Ast + ((size_t)(mb0 + 1) * 32 + (kt)) * 4096 + tid * 8,              \
         &As[bi][1][tid * 8]);                                                \
    GLDS(Ast + ((size_t)(mb0 + 3) * 32 + (kt)) * 4096 + tid * 8,              \
         &As[bi][3][tid * 8]);                                                \
  } while (0)
#define ST_B01(bi, kt)                                                        \
  do {                                                                        \
    GLDS(Wst + ((size_t)(nb0 + 0) * 32 + (kt)) * 4096 + tid * 8,              \
         &Bs[bi][0][tid * 8]);                                                \
    GLDS(Wst + ((size_t)(nb0 + 1) * 32 + (kt)) * 4096 + tid * 8,              \
         &Bs[bi][1][tid * 8]);                                                \
  } while (0)
#define ST_B23(bi, kt)                                                        \
  do {                                                                        \
    GLDS(Wst + ((size_t)(nb0 + 2) * 32 + (kt)) * 4096 + tid * 8,              \
         &Bs[bi][2][tid * 8]);                                                \
    GLDS(Wst + ((size_t)(nb0 + 3) * 32 + (kt)) * 4096 + tid * 8,              \
         &Bs[bi][3][tid * 8]);                                                \
  } while (0)
#define RD_A(dst, bi, half, kc)                                               \
  _Pragma("unroll") for (int i2 = 0; i2 < 4; ++i2) dst[i2] =                  \
      *(const bf8*)(&As[bi][wm * 2 + (half)]                                  \
                       [((i2 * 2 + (kc)) * 4 + ks) * 128 + r * 8]);
#define RD_B(dst, bi, kc)                                                     \
  _Pragma("unroll") for (int j2 = 0; j2 < 4; ++j2) dst[j2] =                  \
      *(const bf8*)(&Bs[bi][wn][((j2 * 2 + (kc)) * 4 + ks) * 128 + r * 8]);
#define MM(ACC, AF, BF)                                                       \
  do {                                                                        \
    __builtin_amdgcn_s_setprio(1);                                            \
    _Pragma("unroll") for (int i3 = 0; i3 < 4; ++i3)                          \
        _Pragma("unroll") for (int j3 = 0; j3 < 4; ++j3) ACC[i3][j3] =        \
            MFMA16(AF[i3], BF[j3], ACC[i3][j3]);                              \
    __builtin_amdgcn_s_setprio(0);                                            \
  } while (0)

  f4 accA[4][4], accB[4][4];
#pragma unroll
  for (int i = 0; i < 4; ++i)
#pragma unroll
    for (int j = 0; j < 4; ++j) {
      accA[i][j] = f4{0.f, 0.f, 0.f, 0.f};
      accB[i][j] = f4{0.f, 0.f, 0.f, 0.f};
    }
  bf8 af[4], b0[4], b1[4];

  ST_A03(0, 0); ST_B01(0, 0); ST_B23(0, 0); ST_A47(0, 0);
  ST_A03(1, 1); ST_B01(1, 1);
  WVM(6);
  SB();

  for (int t = 0; t < 32; ++t) {
    const int buf = t & 1;
    RD_A(af, buf, 0, 0);
    RD_B(b0, buf, 0);
    if (t + 1 < 32) ST_B23(buf ^ 1, t + 1);
    SB();
    MM(accA, af, b0);
    SB();
    RD_A(af, buf, 0, 1);
    RD_B(b1, buf, 1);
    if (t + 1 < 32) ST_A47(buf ^ 1, t + 1);
    SB();
    MM(accA, af, b1);
    if (t + 1 < 32) { WVM(8); } else { WVM(0); }
    SB();
    RD_A(af, buf, 1, 0);
    if (t + 2 < 32) ST_A03(buf, t + 2);
    SB();
    MM(accB, af, b0);
    SB();
    RD_A(af, buf, 1, 1);
    if (t + 2 < 32) ST_B01(buf, t + 2);
    SB();
    MM(accB, af, b1);
    if (t + 2 < 32) { WVM(6); } else if (t + 1 < 32) { WVM(2); }
    SB();
  }

#define EPI(ACC, HALF)                                                        \
  _Pragma("unroll") for (int i = 0; i < 4; ++i)                               \
      _Pragma("unroll") for (int j = 0; j < 4; ++j)                           \
          _Pragma("unroll") for (int rr = 0; rr < 4; ++rr) {                  \
    const int m = mt * 256 + wm * 128 + (HALF)*64 + i * 16 + ks * 4 + rr;     \
    const int n = nt * 256 + wn * 64 + j * 16 + r;                            \
    const float v = ACC[i][j][rr];                                            \
    const int sel = n >> 11, nn = n & 2047, hh = nn >> 7, dd = nn & 127;      \
    const int bb = m >> 10, qq = m & 1023;                                    \
    const u16 bv = f2bf1(v);                                                  \
    if (sel == 0) {                                                           \
      outq[(size_t)m * 2048 + nn] = bv;                                       \
    } else if (sel == 1) {                                                    \
      kg[(((size_t)(bb * 16 + hh) * 50 + (qq >> 5)) * 16 + (dd >> 3)) * 256 + \
         (qq & 31) * 8 + (dd & 7)] = bv;                                      \
    } else {                                                                  \
      vg[((size_t)(bb * 16 + hh) * 200 + (qq >> 3)) * 1024 + dd * 8 +         \
         (qq & 7)] = bv;                                                      \
    }                                                                         \
  }
  EPI(accA, 0)
  EPI(accB, 1)
#undef EPI
}

// ----------------- bf16 MFMA GEMM (m97, modes 1/2 only) ---------------------
template <int MODE>
__global__ __launch_bounds__(256) void gemm_mf(
    const u16* __restrict__ A, const u16* __restrict__ W0,
    const u16* __restrict__ W1, const float* __restrict__ bias0,
    const float* __restrict__ bias1, u16* __restrict__ kg,
    u16* __restrict__ vg, float* __restrict__ outf) {
  __shared__ u16 As2[2][4096];
  __shared__ u16 Ws2[2][4096];
  const int tid = threadIdx.x, lane = tid & 63, w = tid >> 6;
  const int wr = w >> 1, wc = w & 1;
  const int m0 = blockIdx.y * 128, nb = blockIdx.x;
  const u16* Wp;
  if (MODE == 1) Wp = (nb < 16) ? W0 : W1;
  else Wp = W0;
  const int n0l = (MODE == 2 ? nb : (nb & 15)) * 128;
  f4 acc[4][4];
#pragma unroll
  for (int i = 0; i < 4; ++i)
#pragma unroll
    for (int j = 0; j < 4; ++j) acc[i][j] = f4{0.f, 0.f, 0.f, 0.f};
  const int srow = lane >> 2, scol = (lane & 3) * 8;
  const int ch0 = w * 2;
  const u16* Ab = A + (size_t)m0 * 2048 + scol;
  const u16* Wb = Wp + (size_t)n0l * 2048 + scol;
  const int koff = (lane >> 4) * 8;
  const int arow = wr * 64 + (lane & 15), brow = wc * 64 + (lane & 15);

#define GSTAGE(bi, k0)                                                        \
  do {                                                                        \
    _Pragma("unroll") for (int c = 0; c < 2; ++c) {                           \
      const int chunk = ch0 + c;                                              \
      const int row = chunk * 16 + srow;                                      \
      GLDS(Ab + (size_t)row * 2048 + (k0), &As2[bi][chunk * 512 + lane * 8]); \
      GLDS(Wb + (size_t)row * 2048 + (k0), &Ws2[bi][chunk * 512 + lane * 8]); \
    }                                                                         \
  } while (0)

  GSTAGE(0, 0);
  int cur = 0;
  for (int k0 = 0; k0 < 2048; k0 += 32) {
    __syncthreads();
    if (k0 + 32 < 2048) GSTAGE(cur ^ 1, k0 + 32);
    bf8 af2[4], bw[4];
#pragma unroll
    for (int i = 0; i < 4; ++i)
      af2[i] = *(const bf8*)(&As2[cur][(arow + i * 16) * 32 + koff]);
#pragma unroll
    for (int j = 0; j < 4; ++j)
      bw[j] = *(const bf8*)(&Ws2[cur][(brow + j * 16) * 32 + koff]);
#pragma unroll
    for (int i = 0; i < 4; ++i)
#pragma unroll
      for (int j = 0; j < 4; ++j)
        acc[i][j] = MFMA16(af2[i], bw[j], acc[i][j]);
    cur ^= 1;
  }
#undef GSTAGE
  const int rbase = (lane >> 4) * 4;
  const int cql = lane & 15;
#pragma unroll
  for (int i = 0; i < 4; ++i) {
#pragma unroll
    for (int j = 0; j < 4; ++j) {
      const int n = nb * 128 + wc * 64 + j * 16 + cql;
#pragma unroll
      for (int rr = 0; rr < 4; ++rr) {
        const int m = m0 + wr * 64 + i * 16 + rbase + rr;
        float v = acc[i][j][rr];
        if (MODE == 1) {
          const int sel = n >> 11, nn = n & 2047, hh = nn >> 7, dd = nn & 127;
          const int bb = m / 576;
          const int kv = 1024 + (m - bb * 576);
          v += (sel == 0) ? bias0[nn] : bias1[nn];
          const u16 bv = f2bf1(v);
          if (sel == 0) {
            kg[(((size_t)(bb * 16 + hh) * 50 + (kv >> 5)) * 16 + (dd >> 3)) * 256 +
               (kv & 31) * 8 + (dd & 7)] = bv;
          } else {
            vg[((size_t)(bb * 16 + hh) * 200 + (kv >> 3)) * 1024 + dd * 8 +
               (kv & 7)] = bv;
          }
        } else {
          outf[(size_t)m * 2048 + n] = v;
        }
      }
    }
  }
}

// ----------------------- offset network (tiny kernels) ----------------------
__global__ __launch_bounds__(256) void build_lr(const float* __restrict__ hs,
                                                float* __restrict__ lr) {
  int idx = blockIdx.x * 256 + threadIdx.x;
  if (idx >= B * G * CD * K) return;
  int p = idx % K;
  int c = (idx / K) % CD;
  int n = idx / (K * CD);
  int b = n >> 2, g = n & 3;
  lr[idx] = hs[((size_t)b * NQ + p) * C + g * CD + c];
}

__global__ __launch_bounds__(256) void pool_lr(const float* __restrict__ lr,
                                               float* __restrict__ pooled) {
  int row = (blockIdx.x * 256 + threadIdx.x) >> 6;
  int lane = threadIdx.x & 63;
  if (row >= B * G * CD) return;
  const float* p = lr + (size_t)row * K;
  float s = 0.f;
  for (int i = lane; i < K; i += 64) s += p[i];
  for (int o = 32; o; o >>= 1) s += __shfl_xor(s, o);
  if (lane == 0) pooled[row] = s * (1.f / K);
}

__global__ __launch_bounds__(256) void dwconv_silu(const float* __restrict__ lr,
                                                   const float* __restrict__ w,
                                                   float* __restrict__ x1) {
  int idx = blockIdx.x * 256 + threadIdx.x;
  if (idx >= B * G * CD * K) return;
  int p = idx % K;
  int c = (idx / K) % CD;
  int n = idx / (K * CD);
  int y = p / LR, x = p % LR;
  const float* wp = w + c * 9;
  const float* src = lr + ((size_t)n * CD + c) * K;
  float s = 0.f;
#pragma unroll
  for (int dy = -1; dy <= 1; ++dy)
#pragma unroll
    for (int dx = -1; dx <= 1; ++dx) {
      int yy = y + dy, xx = x + dx;
      if (yy < 0 || yy >= LR || xx < 0 || xx >= LR) continue;
      s += src[yy * LR + xx] * wp[(dy + 1) * 3 + dx + 1];
    }
  x1[idx] = s / (1.f + expf(-s));
}

__global__ __launch_bounds__(256) void ln_c512(float* __restrict__ x,
                                               const float* __restrict__ w,
                                               const float* __restrict__ b) {
  const int n = blockIdx.x / 9;
  const int p0 = (blockIdx.x % 9) * 64;
  const int pl = threadIdx.x & 63;
  const int cg = threadIdx.x >> 6;
  float* base = x + (size_t)n * CD * K + p0 + pl;
  float s = 0.f, ss = 0.f;
  for (int c = cg * 128; c < cg * 128 + 128; ++c) {
    float v = base[(size_t)c * K];
    s += v; ss += v * v;
  }
  __shared__ float rs[4][64], rss[4][64];
  rs[cg][pl] = s; rss[cg][pl] = ss;
  __syncthreads();
  float S = rs[0][pl] + rs[1][pl] + rs[2][pl] + rs[3][pl];
  float SS = rss[0][pl] + rss[1][pl] + rss[2][pl] + rss[3][pl];
  const float mean = S * (1.f / CD);
  const float inv = rsqrtf(SS * (1.f / CD) - mean * mean + 1e-5f);
  for (int c = cg * 128; c < cg * 128 + 128; ++c) {
    float v = base[(size_t)c * K];
    base[(size_t)c * K] = (v - mean) * inv * w[c] + b[c];
  }
}

__global__ __launch_bounds__(576) void proj64(const float* __restrict__ x1,
                                              const float* __restrict__ w,
                                              float* __restrict__ x2) {
  const int n = blockIdx.x >> 3;
  const int o0 = (blockIdx.x & 7) * 8;
  const int p = threadIdx.x;
  const float* xb = x1 + (size_t)n * CD * K + p;
  float acc[8] = {0.f, 0.f, 0.f, 0.f, 0.f, 0.f, 0.f, 0.f};
  for (int c = 0; c < CD; ++c) {
    float v = xb[(size_t)c * K];
#pragma unroll
    for (int j = 0; j < 8; ++j) acc[j] += v * w[(o0 + j) * CD + c];
  }
#pragma unroll
  for (int j = 0; j < 8; ++j)
    x2[((size_t)n * INTER + o0 + j) * K + p] = acc[j];
}

__global__ __launch_bounds__(64) void gate_k(const float* __restrict__ pooled,
                                             const float* __restrict__ w,
                                             const float* __restrict__ bias,
                                             float* __restrict__ gate) {
  int idx = blockIdx.x * 64 + threadIdx.x;
  if (idx >= B * G * INTER) return;
  int n = idx >> 6, o = idx & 63;
  const float* pb = pooled + n * CD;
  const float* wb = w + o * CD;
  float s = bias[o];
  for (int c = 0; c < CD; ++c) s += pb[c] * wb[c];
  gate[idx] = 1.f / (1.f + expf(-s));
}

__global__ __launch_bounds__(256) void ln2_off_pos(
    const float* __restrict__ x2, const float* __restrict__ gate,
    const float* __restrict__ ln2w, const float* __restrict__ ln2b,
    const float* __restrict__ offw, float* __restrict__ pos) {
  int wid = (blockIdx.x * 256 + threadIdx.x) >> 6;
  int lane = threadIdx.x & 63;
  if (wid >= B * G * K) return;
  int n = wid / K, p = wid % K;
  float v = x2[((size_t)n * INTER + lane) * K + p] * gate[n * INTER + lane];
  float s = v, ss = v * v;
  for (int o = 32; o; o >>= 1) {
    s += __shfl_xor(s, o);
    ss += __shfl_xor(ss, o);
  }
  float mean = s * (1.f / INTER);
  float var = ss * (1.f / INTER) - mean * mean;
  float xn = (v - mean) * rsqrtf(var + 1e-5f) * ln2w[lane] + ln2b[lane];
  float ox = xn * offw[lane];
  float oy = xn * offw[INTER + lane];
  for (int o = 32; o; o >>= 1) {
    ox += __shfl_xor(ox, o);
    oy += __shfl_xor(oy, o);
  }
  if (lane == 0) {
    int yi = p / LR, xi = p % LR;
    float rx = (xi + 0.5f) / 23.f * 2.f - 1.f;
    float ry = (yi + 0.5f) / 23.f * 2.f - 1.f;
    pos[((size_t)n * K + p) * 2 + 0] = tanhf(rx + ox);
    pos[((size_t)n * K + p) * 2 + 1] = tanhf(ry + oy);
  }
}

__global__ __launch_bounds__(256) void sample_k(const float* __restrict__ img,
                                                const float* __restrict__ pos,
                                                u16* __restrict__ samp) {
  const int bk = blockIdx.x;
  const int b = bk / K, k = bk % K;
  __shared__ int s_idx[G][4];
  __shared__ float s_w[G][4];
  if (threadIdx.x < G) {
    int g = threadIdx.x;
    int n = b * G + g;
    float px = pos[((size_t)n * K + k) * 2 + 0];
    float py = pos[((size_t)n * K + k) * 2 + 1];
    float x = (px + 1.f) * 0.5f * (HR - 1);
    float y = (py + 1.f) * 0.5f * (HR - 1);
    float x0f = floorf(x), y0f = floorf(y);
    float wx = x - x0f, wy = y - y0f;
    int x0 = min(max((int)x0f, 0), HR - 1);
    int x1 = min(x0 + 1, HR - 1);
    int y0 = min(max((int)y0f, 0), HR - 1);
    int y1 = min(y0 + 1, HR - 1);
    s_idx[g][0] = y0 * HR + x0;
    s_idx[g][1] = y0 * HR + x1;
    s_idx[g][2] = y1 * HR + x0;
    s_idx[g][3] = y1 * HR + x1;
    s_w[g][0] = (1.f - wx) * (1.f - wy);
    s_w[g][1] = wx * (1.f - wy);
    s_w[g][2] = (1.f - wx) * wy;
    s_w[g][3] = wx * wy;
  }
  __syncthreads();
  const float* ib = img + (size_t)b * HR * HR * C;
  u16* ob = samp + ((size_t)b * K + k) * C;
  for (int ch = threadIdx.x; ch < C; ch += 256) {
    int g = ch >> 9;
    float v = s_w[g][0] * ib[(size_t)s_idx[g][0] * C + ch] +
              s_w[g][1] * ib[(size_t)s_idx[g][1] * C + ch] +
              s_w[g][2] * ib[(size_t)s_idx[g][2] * C + ch] +
              s_w[g][3] * ib[(size_t)s_idx[g][3] * C + ch];
    ob[ch] = f2bf1(v);
  }
}

// ---------------- KV-split MFMA flash attention (partials) ------------------
// grid 1024: blocks [0,512) = fam A (causal text kv 0..1024), [512,1024) =
// fam B (HD kv 1024..1600, no mask). Each computes unnormalized O + (m,l).
__global__ __launch_bounds__(256) void attn_part(
    const u16* __restrict__ qb, const u16* __restrict__ kg,
    const u16* __restrict__ vg, float* __restrict__ oA,
    float* __restrict__ oB, float* __restrict__ mlA,
    float* __restrict__ mlB) {
  const int i = blockIdx.x;
  const int fam = i >> 9;
  const int r9 = i & 511;
  int bh, qblk;
  if (fam == 0) {  // balanced remap: i and i+256 get complementary causal work
    const int pair = r9 & 255, half = r9 >> 8;
    bh = pair & 31;
    const int q8 = pair >> 5;
    qblk = half ? (15 - q8) : q8;
  } else {
    bh = r9 & 31;
    qblk = r9 >> 5;
  }
  const int b = bh >> 4, h = bh & 15;
  const int q0 = qblk * 64;
  const int tid = threadIdx.x, lane = tid & 63, w = tid >> 6;
  const int qw = q0 + w * 16;
  const int col = lane & 15, kpart = lane >> 4, rbase = kpart * 4;
  __shared__ u16 Ks[2][4096];     // [dblk16][kv32][8]
  __shared__ u16 Vs[2][4096];     // [kvblk4][d128][8]
  __shared__ u16 Pl[4][16 * 40];  // P per wave, row stride 40 (16B-aligned)
  float* oacc = fam ? oB : oA;
  float* ml = fam ? mlB : mlA;
  bf8 qf[4];
  {
    const u16* qp =
        qb + (size_t)(b * 1024 + qw + col) * 2048 + h * 128 + kpart * 8;
#pragma unroll
    for (int dc = 0; dc < 4; ++dc) qf[dc] = *(const bf8*)(qp + dc * 32);
  }
  f4 o[8];
#pragma unroll
  for (int df = 0; df < 8; ++df) o[df] = f4{0.f, 0.f, 0.f, 0.f};
  float m_r[4] = {-1e30f, -1e30f, -1e30f, -1e30f};
  float l_r[4] = {0.f, 0.f, 0.f, 0.f};
  const float scale = 0.08838834764831845f;
  const int nt = fam ? 18 : ((q0 + 64) >> 5);
  const int kvadd = fam ? 1024 : 0;
  const u16* kbh = kg + (size_t)bh * (NKV * 128);
  const u16* vbh = vg + (size_t)bh * (NKV * 128);
  u16* pw = &Pl[w][0];

#define ASTAGE(bi, kv0)                                                       \
  do {                                                                        \
    const u16* gk = kbh + (size_t)((kv0) >> 5) * 4096 + w * 1024 + lane * 8;  \
    GLDS(gk, &Ks[bi][w * 1024 + lane * 8]);                                   \
    GLDS(gk + 512, &Ks[bi][w * 1024 + 512 + lane * 8]);                       \
    const u16* gv = vbh + (size_t)((kv0) >> 3) * 1024 + w * 1024 + lane * 8;  \
    GLDS(gv, &Vs[bi][w * 1024 + lane * 8]);                                   \
    GLDS(gv + 512, &Vs[bi][w * 1024 + 512 + lane * 8]);                       \
  } while (0)

  ASTAGE(0, kvadd);
  int cur = 0;
  for (int t = 0; t < nt; ++t) {
    const int kv0 = kvadd + (t << 5);
    __syncthreads();
    if (t + 1 < nt) ASTAGE(cur ^ 1, kvadd + ((t + 1) << 5));
    const u16* ksb = &Ks[cur][0];
    const u16* vsb = &Vs[cur][0];
    f4 s0 = {0.f, 0.f, 0.f, 0.f}, s1 = {0.f, 0.f, 0.f, 0.f};
    __builtin_amdgcn_s_setprio(1);
#pragma unroll
    for (int dc = 0; dc < 4; ++dc) {
      const int dblk = dc * 4 + kpart;
      bf8 k0f = *(const bf8*)(ksb + (dblk * 32 + col) * 8);
      bf8 k1f = *(const bf8*)(ksb + (dblk * 32 + 16 + col) * 8);
      s0 = MFMA16(qf[dc], k0f, s0);
      s1 = MFMA16(qf[dc], k1f, s1);
    }
    __builtin_amdgcn_s_setprio(0);
    float sa[4], sc[4], mxr[4], p0[4], p1[4];
    bool grow = false;
    const bool need_mask = (fam == 0) && (kv0 + 31 > qw);
#pragma unroll
    for (int rr = 0; rr < 4; ++rr) {
      float a = s0[rr] * scale, c2 = s1[rr] * scale;
      if (need_mask) {
        const int qg = qw + rbase + rr;
        if (kv0 + col > qg) a = -1e30f;
        if (kv0 + 16 + col > qg) c2 = -1e30f;
      }
      sa[rr] = a; sc[rr] = c2;
      float mx = fmaxf(a, c2);
      mx = fmaxf(mx, __shfl_xor(mx, 1));
      mx = fmaxf(mx, __shfl_xor(mx, 2));
      mx = fmaxf(mx, __shfl_xor(mx, 4));
      mx = fmaxf(mx, __shfl_xor(mx, 8));
      mxr[rr] = mx;
      grow |= (mx > m_r[rr] + 8.f);
    }
    if (__any(grow)) {
      float fr[4];
#pragma unroll
      for (int rr = 0; rr < 4; ++rr) {
        const float mn = fmaxf(m_r[rr], mxr[rr]);
        fr[rr] = __expf(m_r[rr] - mn);
        m_r[rr] = mn;
        p0[rr] = __expf(sa[rr] - mn);
        p1[rr] = __expf(sc[rr] - mn);
        float ps = p0[rr] + p1[rr];
        ps += __shfl_xor(ps, 1);
        ps += __shfl_xor(ps, 2);
        ps += __shfl_xor(ps, 4);
        ps += __shfl_xor(ps, 8);
        l_r[rr] = l_r[rr] * fr[rr] + ps;
      }
#pragma unroll
      for (int df = 0; df < 8; ++df) {
        o[df][0] *= fr[0]; o[df][1] *= fr[1];
        o[df][2] *= fr[2]; o[df][3] *= fr[3];
      }
    } else {  // defer-max (P bounded by e^8)
#pragma unroll
      for (int rr = 0; rr < 4; ++rr) {
        p0[rr] = __expf(sa[rr] - m_r[rr]);
        p1[rr] = __expf(sc[rr] - m_r[rr]);
        float ps = p0[rr] + p1[rr];
        ps += __shfl_xor(ps, 1);
        ps += __shfl_xor(ps, 2);
        ps += __shfl_xor(ps, 4);
        ps += __shfl_xor(ps, 8);
        l_r[rr] += ps;
      }
    }
#pragma unroll
    for (int rr = 0; rr < 4; ++rr) {
      pw[(rbase + rr) * 40 + col] = f2bf1(p0[rr]);
      pw[(rbase + rr) * 40 + 16 + col] = f2bf1(p1[rr]);
    }
    bf8 pa = *(const bf8*)(pw + col * 40 + kpart * 8);
    __builtin_amdgcn_s_setprio(1);
#pragma unroll
    for (int df = 0; df < 8; ++df) {
      bf8 vf = *(const bf8*)(vsb + (kpart * 128 + df * 16 + col) * 8);
      o[df] = MFMA16(pa, vf, o[df]);
    }
    __builtin_amdgcn_s_setprio(0);
    cur ^= 1;
  }
#undef ASTAGE
  float* orow = oacc + (size_t)(bh * 1024 + qw + rbase) * 128 + col;
#pragma unroll
  for (int df = 0; df < 8; ++df)
#pragma unroll
    for (int rr = 0; rr < 4; ++rr)
      orow[(size_t)rr * 128 + df * 16] = o[df][rr];
  if (col == 0) {
#pragma unroll
    for (int rr = 0; rr < 4; ++rr) {
      const int row = bh * 1024 + qw + rbase + rr;
      ml[row * 2] = m_r[rr];
      ml[row * 2 + 1] = l_r[rr];
    }
  }
}

// merge partials -> aob bf16
__global__ __launch_bounds__(256) void attn_merge(
    const float* __restrict__ oA, const float* __restrict__ mlA,
    const float* __restrict__ oB, const float* __restrict__ mlB,
    u16* __restrict__ aob) {
  const int gid = blockIdx.x * 256 + threadIdx.x;
  const int row = gid >> 5;       // bh*1024 + q
  const int d0 = (gid & 31) * 4;
  const float mA = mlA[row * 2], lA = mlA[row * 2 + 1];
  const float mB = mlB[row * 2], lB = mlB[row * 2 + 1];
  const float m = fmaxf(mA, mB);
  const float wA = __expf(mA - m), wB = __expf(mB - m);
  const float inv = 1.f / (lA * wA + lB * wB);
  const f4 a = *(const f4*)(oA + (size_t)row * 128 + d0);
  const f4 c = *(const f4*)(oB + (size_t)row * 128 + d0);
  const int bh = row >> 10, q = row & 1023;
  const int bb = bh >> 4, h = bh & 15;
  u16* dst = aob + (size_t)(bb * 1024 + q) * 2048 + h * 128 + d0;
#pragma unroll
  for (int j = 0; j < 4; ++j)
    dst[j] = f2bf1((a[j] * wA + c[j] * wB) * inv);
}

// ---------------------------------------------------------------------------
extern "C" void kernel_launch(void* const* d_in, const int* in_sizes, int n_in,
                              void* d_out, int out_size, void* d_ws,
                              size_t ws_size, hipStream_t stream) {
  const float* hs = (const float*)d_in[0];
  const float* img = (const float*)d_in[1];
  const float* wq = (const float*)d_in[2];
  const float* wk = (const float*)d_in[3];
  const float* wv = (const float*)d_in[4];
  const float* wo = (const float*)d_in[5];
  const float* cdw = (const float*)d_in[6];
  const float* ln1w = (const float*)d_in[7];
  const float* ln1b = (const float*)d_in[8];
  const float* plrw = (const float*)d_in[9];
  const float* piw = (const float*)d_in[10];
  const float* pib = (const float*)d_in[11];
  const float* ln2w = (const float*)d_in[12];
  const float* ln2b = (const float*)d_in[13];
  const float* offw = (const float*)d_in[14];
  const float* khw = (const float*)d_in[15];
  const float* khb = (const float*)d_in[16];
  const float* vhw = (const float*)d_in[17];
  const float* vhb = (const float*)d_in[18];
  float* outp = (float*)d_out;

  u16* wsp = (u16*)d_ws;
  const size_t SZ = 4194304;  // 2048*2048
  u16* hs_st = wsp;            // staged
  u16* wq_st = wsp + SZ;       // staged; reused as aob_bf after gemm256
  u16* wk_st = wsp + 2 * SZ;   // staged; oA overlay after gemm256
  u16* wv_st = wsp + 3 * SZ;   // staged; oA overlay after gemm256
  u16* wo_bf = wsp + 4 * SZ;   // row-major (live until gemm2)
  u16* khw_bf = wsp + 5 * SZ;  // row-major; oB overlay after gemm1
  u16* vhw_bf = wsp + 6 * SZ;  // row-major; oB overlay after gemm1
  u16* qb_bf = wsp + 7 * SZ;
  u16* samp_bf = wsp + 8 * SZ;       // 1152*2048 row-major
  u16* kg = wsp + 8 * SZ + 2359296;  // 2*16*1600*128
  u16* vg = kg + 6553600;
  float* lrb = (float*)kg;  // fp32 scratch overlaps kg/vg (dead before gemms)
  float* x1b = lrb + 2359296;
  float* x2b = x1b + 2359296;
  float* poolb = x2b + 294912;
  float* gb = poolb + 4096;
  float* posb = (float*)(vg + 6553600);  // 9216 floats
  float* mlA = posb + 9216;              // 65536 floats
  float* mlB = mlA + 65536;              // 65536 floats
  float* oA = (float*)(wsp + 2 * SZ);    // 4M floats over wk_st+wv_st
  float* oB = (float*)(wsp + 5 * SZ);    // 4M floats over khw_bf+vhw_bf
  u16* aob_bf = wq_st;

  dim3 blk(256);
  // ---- offset network ----
  build_lr<<<dim3((B * G * CD * K) / 256), blk, 0, stream>>>(hs, lrb);
  pool_lr<<<dim3((B * G * CD) / 4), blk, 0, stream>>>(lrb, poolb);
  dwconv_silu<<<dim3((B * G * CD * K) / 256), blk, 0, stream>>>(lrb, cdw, x1b);
  ln_c512<<<dim3(B * G * 9), blk, 0, stream>>>(x1b, ln1w, ln1b);
  proj64<<<dim3(B * G * 8), dim3(576), 0, stream>>>(x1b, plrw, x2b);
  gate_k<<<dim3((B * G * INTER) / 64), dim3(64), 0, stream>>>(poolb, piw, pib,
                                                              gb);
  ln2_off_pos<<<dim3((B * G * K) / 4), blk, 0, stream>>>(x2b, gb, ln2w, ln2b,
                                                         offw, posb);
  sample_k<<<dim3(B * K), blk, 0, stream>>>(img, posb, samp_bf);

  // ---- bf16 conversions (fused; 0-3 staged via LDS transpose) ----
  f2bf_k7<<<dim3(1024, 7), blk, 0, stream>>>(hs, wq, wk, wv, wo, khw, vhw,
                                             hs_st, wq_st, wk_st, wv_st,
                                             wo_bf, khw_bf, vhw_bf);

  // ---- MFMA GEMMs ----
  gemm256<<<dim3(192), dim3(512), 0, stream>>>(hs_st, wq_st, wk_st, wv_st,
                                               qb_bf, kg, vg);
  gemm_mf<1><<<dim3(32, 9), blk, 0, stream>>>(samp_bf, khw_bf, vhw_bf, khb,
                                              vhb, kg, vg, nullptr);
  // ---- attention (KV-split partials + merge) ----
  attn_part<<<dim3(1024), blk, 0, stream>>>(qb_bf, kg, vg, oA, oB, mlA, mlB);
  attn_merge<<<dim3(4096), blk, 0, stream>>>(oA, mlA, oB, mlB, aob_bf);
  // ---- output projection ----
  gemm_mf<2><<<dim3(16, 16), blk, 0, stream>>>(aob_bf, wo_bf, nullptr, nullptr,
                                               nullptr, nullptr, nullptr,
                                               outp);
}

// Round 6
// 367.771 us; speedup vs baseline: 1.1993x; 1.1450x over previous
//
#include <hip/hip_runtime.h>

typedef unsigned short u16;
typedef unsigned int u32;
typedef __attribute__((ext_vector_type(8))) short bf8;
typedef __attribute__((ext_vector_type(4))) float f4;
typedef __attribute__((ext_vector_type(4))) unsigned short us4;

constexpr int B = 2;
constexpr int NQ = 1024;
constexpr int C = 2048;
constexpr int DH = 128;
constexpr int G = 4;
constexpr int CD = 512;
constexpr int LR = 24;
constexpr int HR = 72;
constexpr int INTER = 64;
constexpr int K = LR * LR;  // 576
constexpr int NKV = NQ + K; // 1600

#define MFMA16(a, b, c) __builtin_amdgcn_mfma_f32_16x16x32_bf16(a, b, c, 0, 0, 0)
#define GLDS(g, l)                                                         \
  __builtin_amdgcn_global_load_lds(                                        \
      (const __attribute__((address_space(1))) void*)(g),                  \
      (__attribute__((address_space(3))) void*)(l), 16, 0, 0)

__device__ __forceinline__ u16 f2bf1(float f) {
  u32 u = __float_as_uint(f);
  u32 r = (u + 0x7fffu + ((u >> 16) & 1u)) >> 16;
  return (u16)r;
}

// --------------------- fused fp32 -> bf16 (7 tensors) -----------------------
__global__ __launch_bounds__(256) void f2bf_k7(
    const float* __restrict__ s0, const float* __restrict__ s1,
    const float* __restrict__ s2, const float* __restrict__ s3,
    const float* __restrict__ s4, const float* __restrict__ s5,
    const float* __restrict__ s6, u16* __restrict__ d0, u16* __restrict__ d1,
    u16* __restrict__ d2, u16* __restrict__ d3, u16* __restrict__ d4,
    u16* __restrict__ d5, u16* __restrict__ d6) {
  __shared__ u16 L[64][68];
  const int y = blockIdx.y;
  const float* s;
  u16* d;
  switch (y) {
    case 0: s = s0; d = d0; break;
    case 1: s = s1; d = d1; break;
    case 2: s = s2; d = d2; break;
    case 3: s = s3; d = d3; break;
    case 4: s = s4; d = d4; break;
    case 5: s = s5; d = d5; break;
    default: s = s6; d = d6; break;
  }
  const int t = threadIdx.x;
  if (y < 4) {
    const int pc = blockIdx.x;  // piece 0..1023
    const int mb = pc >> 5, kb = pc & 31;
    const int rin = t >> 2, c0 = (t & 3) * 16;
    const float* src = s + (size_t)(mb * 64 + rin) * 2048 + kb * 64 + c0;
#pragma unroll
    for (int j = 0; j < 16; j += 4) {
      float4 v = *(const float4*)(src + j);
      L[rin][c0 + j] = f2bf1(v.x);
      L[rin][c0 + j + 1] = f2bf1(v.y);
      L[rin][c0 + j + 2] = f2bf1(v.z);
      L[rin][c0 + j + 3] = f2bf1(v.w);
    }
    __syncthreads();
    u16* dst = d + (size_t)pc * 4096 + t * 16;
#pragma unroll
    for (int gg = 0; gg < 2; ++gg) {
      const int g = t * 2 + gg;
      const int rh = g & 15, ks2 = (g >> 4) & 3, kc = (g >> 6) & 1, fr = g >> 7;
      const int row = fr * 16 + rh, cc = kc * 32 + ks2 * 8;
      us4 o0, o1;
      o0.x = L[row][cc];     o0.y = L[row][cc + 1];
      o0.z = L[row][cc + 2]; o0.w = L[row][cc + 3];
      o1.x = L[row][cc + 4]; o1.y = L[row][cc + 5];
      o1.z = L[row][cc + 6]; o1.w = L[row][cc + 7];
      *(us4*)(dst + gg * 8) = o0;
      *(us4*)(dst + gg * 8 + 4) = o1;
    }
  } else {
    const size_t i0 = ((size_t)blockIdx.x * 256 + t) * 16;
#pragma unroll
    for (int j = 0; j < 16; j += 4) {
      float4 v = *(const float4*)(s + i0 + j);
      us4 o;
      o.x = f2bf1(v.x); o.y = f2bf1(v.y); o.z = f2bf1(v.z); o.w = f2bf1(v.w);
      *(us4*)(d + i0 + j) = o;
    }
  }
}

// --------- fused GEMM: blocks 0-191 = QKV 256x256 8-phase (staged);
// --------- blocks 192-335 = HD k/v dual-128x128 m97 path (row-major samp).
#define SB()                               \
  do {                                     \
    __builtin_amdgcn_sched_barrier(0);     \
    __builtin_amdgcn_s_barrier();          \
    __builtin_amdgcn_sched_barrier(0);     \
  } while (0)
#define WVM(n) asm volatile("s_waitcnt vmcnt(" #n ")" ::: "memory")

__global__ __launch_bounds__(512, 2) void gemm_fused(
    const u16* __restrict__ Ast, const u16* __restrict__ Wq,
    const u16* __restrict__ Wk, const u16* __restrict__ Wv,
    const u16* __restrict__ samp, const u16* __restrict__ khw,
    const u16* __restrict__ vhw, const float* __restrict__ khb,
    const float* __restrict__ vhb, u16* __restrict__ outq,
    u16* __restrict__ kg, u16* __restrict__ vg) {
  __shared__ u16 As[2][4][4096];
  __shared__ u16 Bs[2][4][4096];
  const int tid = threadIdx.x, lane = tid & 63, w = tid >> 6;
  const int ks = lane >> 4, r = lane & 15;
  const int bid = blockIdx.x;

  if (bid < 192) {
    // ======================= QKV 256x256 8-phase =========================
    const int wm = w >> 2, wn = w & 3;
    const int swz = (bid & 7) * 24 + (bid >> 3);
    const int mt = swz / 24, nt = swz % 24;
    const u16* Wst = (nt < 8) ? Wq : (nt < 16) ? Wk : Wv;
    const int nb0 = (nt & 7) * 4;
    const int mb0 = mt * 4;

#define ST_A03(bi, kt)                                                        \
  do {                                                                        \
    GLDS(Ast + ((size_t)(mb0 + 0) * 32 + (kt)) * 4096 + tid * 8,              \
         &As[bi][0][tid * 8]);                                                \
    GLDS(Ast + ((size_t)(mb0 + 2) * 32 + (kt)) * 4096 + tid * 8,              \
         &As[bi][2][tid * 8]);                                                \
  } while (0)
#define ST_A47(bi, kt)                                                        \
  do {                                                                        \
    GLDS(Ast + ((size_t)(mb0 + 1) * 32 + (kt)) * 4096 + tid * 8,              \
         &As[bi][1][tid * 8]);                                                \
    GLDS(Ast + ((size_t)(mb0 + 3) * 32 + (kt)) * 4096 + tid * 8,              \
         &As[bi][3][tid * 8]);                                                \
  } while (0)
#define ST_B01(bi, kt)                                                        \
  do {                                                                        \
    GLDS(Wst + ((size_t)(nb0 + 0) * 32 + (kt)) * 4096 + tid * 8,              \
         &Bs[bi][0][tid * 8]);                                                \
    GLDS(Wst + ((size_t)(nb0 + 1) * 32 + (kt)) * 4096 + tid * 8,              \
         &Bs[bi][1][tid * 8]);                                                \
  } while (0)
#define ST_B23(bi, kt)                                                        \
  do {                                                                        \
    GLDS(Wst + ((size_t)(nb0 + 2) * 32 + (kt)) * 4096 + tid * 8,              \
         &Bs[bi][2][tid * 8]);                                                \
    GLDS(Wst + ((size_t)(nb0 + 3) * 32 + (kt)) * 4096 + tid * 8,              \
         &Bs[bi][3][tid * 8]);                                                \
  } while (0)
#define RD_A(dst, bi, half, kc)                                               \
  _Pragma("unroll") for (int i2 = 0; i2 < 4; ++i2) dst[i2] =                  \
      *(const bf8*)(&As[bi][wm * 2 + (half)]                                  \
                       [((i2 * 2 + (kc)) * 4 + ks) * 128 + r * 8]);
#define RD_B(dst, bi, kc)                                                     \
  _Pragma("unroll") for (int j2 = 0; j2 < 4; ++j2) dst[j2] =                  \
      *(const bf8*)(&Bs[bi][wn][((j2 * 2 + (kc)) * 4 + ks) * 128 + r * 8]);
#define MM(ACC, AF, BF)                                                       \
  do {                                                                        \
    __builtin_amdgcn_s_setprio(1);                                            \
    _Pragma("unroll") for (int i3 = 0; i3 < 4; ++i3)                          \
        _Pragma("unroll") for (int j3 = 0; j3 < 4; ++j3) ACC[i3][j3] =        \
            MFMA16(AF[i3], BF[j3], ACC[i3][j3]);                              \
    __builtin_amdgcn_s_setprio(0);                                            \
  } while (0)

    f4 accA[4][4], accB[4][4];
#pragma unroll
    for (int i = 0; i < 4; ++i)
#pragma unroll
      for (int j = 0; j < 4; ++j) {
        accA[i][j] = f4{0.f, 0.f, 0.f, 0.f};
        accB[i][j] = f4{0.f, 0.f, 0.f, 0.f};
      }
    bf8 af[4], b0[4], b1[4];

    ST_A03(0, 0); ST_B01(0, 0); ST_B23(0, 0); ST_A47(0, 0);
    ST_A03(1, 1); ST_B01(1, 1);
    WVM(6);
    SB();

    for (int t = 0; t < 32; ++t) {
      const int buf = t & 1;
      RD_A(af, buf, 0, 0);
      RD_B(b0, buf, 0);
      if (t + 1 < 32) ST_B23(buf ^ 1, t + 1);
      SB();
      MM(accA, af, b0);
      SB();
      RD_A(af, buf, 0, 1);
      RD_B(b1, buf, 1);
      if (t + 1 < 32) ST_A47(buf ^ 1, t + 1);
      SB();
      MM(accA, af, b1);
      if (t + 1 < 32) { WVM(8); } else { WVM(0); }
      SB();
      RD_A(af, buf, 1, 0);
      if (t + 2 < 32) ST_A03(buf, t + 2);
      SB();
      MM(accB, af, b0);
      SB();
      RD_A(af, buf, 1, 1);
      if (t + 2 < 32) ST_B01(buf, t + 2);
      SB();
      MM(accB, af, b1);
      if (t + 2 < 32) { WVM(6); } else if (t + 1 < 32) { WVM(2); }
      SB();
    }

#define EPI(ACC, HALF)                                                        \
  _Pragma("unroll") for (int i = 0; i < 4; ++i)                               \
      _Pragma("unroll") for (int j = 0; j < 4; ++j)                           \
          _Pragma("unroll") for (int rr = 0; rr < 4; ++rr) {                  \
    const int m = mt * 256 + wm * 128 + (HALF)*64 + i * 16 + ks * 4 + rr;     \
    const int n = nt * 256 + wn * 64 + j * 16 + r;                            \
    const float v = ACC[i][j][rr];                                            \
    const int sel = n >> 11, nn = n & 2047, hh = nn >> 7, dd = nn & 127;      \
    const int bb = m >> 10, qq = m & 1023;                                    \
    const u16 bv = f2bf1(v);                                                  \
    if (sel == 0) {                                                           \
      outq[(size_t)m * 2048 + nn] = bv;                                       \
    } else if (sel == 1) {                                                    \
      kg[(((size_t)(bb * 16 + hh) * 50 + (qq >> 5)) * 16 + (dd >> 3)) * 256 + \
         (qq & 31) * 8 + (dd & 7)] = bv;                                      \
    } else {                                                                  \
      vg[((size_t)(bb * 16 + hh) * 200 + (qq >> 3)) * 1024 + dd * 8 +         \
         (qq & 7)] = bv;                                                      \
    }                                                                         \
  }
    EPI(accA, 0)
    EPI(accB, 1)
#undef EPI
  } else {
    // =================== HD k/v dual 128x128 (m97 2-phase) =================
    const int hb = bid - 192;  // 0..143
    const int mt = hb >> 4, nb = hb & 15;
    const int m0 = mt * 128, n0l = nb * 128;
    const int srow = lane >> 2, scol = (lane & 3) * 8;
    const int wh = w & 3;               // wave index within half
    const int wr = wh >> 1, wc = wh & 1;
    const bool is_v = (w >= 4);
    const u16* Wp = is_v ? vhw : khw;
    const float* bias = is_v ? vhb : khb;

#define HDST(bi, k0)                                                          \
  do {                                                                        \
    GLDS(samp + (size_t)(m0 + w * 16 + srow) * 2048 + scol + (k0),            \
         &As[bi][0][w * 512 + lane * 8]);                                     \
    GLDS(Wp + (size_t)(n0l + wh * 32 + srow) * 2048 + scol + (k0),            \
         &Bs[bi][is_v ? 1 : 0][wh * 1024 + lane * 8]);                        \
    GLDS(Wp + (size_t)(n0l + wh * 32 + 16 + srow) * 2048 + scol + (k0),       \
         &Bs[bi][is_v ? 1 : 0][wh * 1024 + 512 + lane * 8]);                  \
  } while (0)

    f4 acc[4][4];
#pragma unroll
    for (int i = 0; i < 4; ++i)
#pragma unroll
      for (int j = 0; j < 4; ++j) acc[i][j] = f4{0.f, 0.f, 0.f, 0.f};
    const int koff = ks * 8;
    const int arow = wr * 64 + r, brow = wc * 64 + r;
    const u16* Wsb = &Bs[0][is_v ? 1 : 0][0] - 0;  // indexed via bi below

    HDST(0, 0);
    int cur = 0;
    for (int k0 = 0; k0 < 2048; k0 += 32) {
      __syncthreads();
      if (k0 + 32 < 2048) HDST(cur ^ 1, k0 + 32);
      bf8 af2[4], bw[4];
#pragma unroll
      for (int i = 0; i < 4; ++i)
        af2[i] = *(const bf8*)(&As[cur][0][(arow + i * 16) * 32 + koff]);
#pragma unroll
      for (int j = 0; j < 4; ++j)
        bw[j] =
            *(const bf8*)(&Bs[cur][is_v ? 1 : 0][(brow + j * 16) * 32 + koff]);
#pragma unroll
      for (int i = 0; i < 4; ++i)
#pragma unroll
        for (int j = 0; j < 4; ++j)
          acc[i][j] = MFMA16(af2[i], bw[j], acc[i][j]);
      cur ^= 1;
    }
#undef HDST
    const int rbase = ks * 4;
#pragma unroll
    for (int i = 0; i < 4; ++i) {
#pragma unroll
      for (int j = 0; j < 4; ++j) {
        const int nn = n0l + wc * 64 + j * 16 + r;
        const int hh = nn >> 7, dd = nn & 127;
#pragma unroll
        for (int rr = 0; rr < 4; ++rr) {
          const int m = m0 + wr * 64 + i * 16 + rbase + rr;
          const int bb = m / 576;
          const int kv = 1024 + (m - bb * 576);
          const u16 bv = f2bf1(acc[i][j][rr] + bias[nn]);
          if (!is_v) {
            kg[(((size_t)(bb * 16 + hh) * 50 + (kv >> 5)) * 16 + (dd >> 3)) *
                   256 +
               (kv & 31) * 8 + (dd & 7)] = bv;
          } else {
            vg[((size_t)(bb * 16 + hh) * 200 + (kv >> 3)) * 1024 + dd * 8 +
               (kv & 7)] = bv;
          }
        }
      }
    }
  }
}

// ----------------- bf16 MFMA GEMM (m97, output proj only) -------------------
__global__ __launch_bounds__(256) void gemm_out(const u16* __restrict__ A,
                                                const u16* __restrict__ W0,
                                                float* __restrict__ outf) {
  __shared__ u16 As2[2][4096];
  __shared__ u16 Ws2[2][4096];
  const int tid = threadIdx.x, lane = tid & 63, w = tid >> 6;
  const int wr = w >> 1, wc = w & 1;
  const int m0 = blockIdx.y * 128, nb = blockIdx.x;
  const int n0l = nb * 128;
  f4 acc[4][4];
#pragma unroll
  for (int i = 0; i < 4; ++i)
#pragma unroll
    for (int j = 0; j < 4; ++j) acc[i][j] = f4{0.f, 0.f, 0.f, 0.f};
  const int srow = lane >> 2, scol = (lane & 3) * 8;
  const int ch0 = w * 2;
  const u16* Ab = A + (size_t)m0 * 2048 + scol;
  const u16* Wb = W0 + (size_t)n0l * 2048 + scol;
  const int koff = (lane >> 4) * 8;
  const int arow = wr * 64 + (lane & 15), brow = wc * 64 + (lane & 15);

#define GSTAGE(bi, k0)                                                        \
  do {                                                                        \
    _Pragma("unroll") for (int c = 0; c < 2; ++c) {                           \
      const int chunk = ch0 + c;                                              \
      const int row = chunk * 16 + srow;                                      \
      GLDS(Ab + (size_t)row * 2048 + (k0), &As2[bi][chunk * 512 + lane * 8]); \
      GLDS(Wb + (size_t)row * 2048 + (k0), &Ws2[bi][chunk * 512 + lane * 8]); \
    }                                                                         \
  } while (0)

  GSTAGE(0, 0);
  int cur = 0;
  for (int k0 = 0; k0 < 2048; k0 += 32) {
    __syncthreads();
    if (k0 + 32 < 2048) GSTAGE(cur ^ 1, k0 + 32);
    bf8 af2[4], bw[4];
#pragma unroll
    for (int i = 0; i < 4; ++i)
      af2[i] = *(const bf8*)(&As2[cur][(arow + i * 16) * 32 + koff]);
#pragma unroll
    for (int j = 0; j < 4; ++j)
      bw[j] = *(const bf8*)(&Ws2[cur][(brow + j * 16) * 32 + koff]);
#pragma unroll
    for (int i = 0; i < 4; ++i)
#pragma unroll
      for (int j = 0; j < 4; ++j)
        acc[i][j] = MFMA16(af2[i], bw[j], acc[i][j]);
    cur ^= 1;
  }
#undef GSTAGE
  const int rbase = (lane >> 4) * 4;
  const int cql = lane & 15;
#pragma unroll
  for (int i = 0; i < 4; ++i)
#pragma unroll
    for (int j = 0; j < 4; ++j) {
      const int n = n0l + wc * 64 + j * 16 + cql;
#pragma unroll
      for (int rr = 0; rr < 4; ++rr) {
        const int m = m0 + wr * 64 + i * 16 + rbase + rr;
        outf[(size_t)m * 2048 + n] = acc[i][j][rr];
      }
    }
}

// ----------------------- offset network (tiny kernels) ----------------------
// coalesced hs -> lr transpose via LDS
__global__ __launch_bounds__(256) void build_lr_t(const float* __restrict__ hs,
                                                  float* __restrict__ lr) {
  __shared__ float L[32][65];
  const int bidx = blockIdx.x;  // 8 n * 9 pb * 16 cb = 1152
  const int n = bidx / 144;
  const int rem = bidx % 144;
  const int pb = rem / 16, cb = rem % 16;
  const int b = n >> 2, g = n & 3;
  const int p0 = pb * 64, c0 = cb * 32;
  const int t = threadIdx.x;
  const int cl = t & 31, pr = t >> 5;
#pragma unroll
  for (int it = 0; it < 8; ++it) {
    const int p = p0 + it * 8 + pr;
    L[cl][it * 8 + pr] =
        hs[((size_t)(b * 1024 + p)) * 2048 + g * 512 + c0 + cl];
  }
  __syncthreads();
  const int pl = t & 63, cr = t >> 6;
#pragma unroll
  for (int jt = 0; jt < 8; ++jt) {
    const int c = jt * 4 + cr;
    lr[((size_t)(n * 512) + c0 + c) * 576 + p0 + pl] = L[c][pl];
  }
}

__global__ __launch_bounds__(256) void pool_lr(const float* __restrict__ lr,
                                               float* __restrict__ pooled) {
  int row = (blockIdx.x * 256 + threadIdx.x) >> 6;
  int lane = threadIdx.x & 63;
  if (row >= B * G * CD) return;
  const float* p = lr + (size_t)row * K;
  float s = 0.f;
  for (int i = lane; i < K; i += 64) s += p[i];
  for (int o = 32; o; o >>= 1) s += __shfl_xor(s, o);
  if (lane == 0) pooled[row] = s * (1.f / K);
}

__global__ __launch_bounds__(256) void dwconv_silu(const float* __restrict__ lr,
                                                   const float* __restrict__ w,
                                                   float* __restrict__ x1) {
  int idx = blockIdx.x * 256 + threadIdx.x;
  if (idx >= B * G * CD * K) return;
  int p = idx % K;
  int c = (idx / K) % CD;
  int n = idx / (K * CD);
  int y = p / LR, x = p % LR;
  const float* wp = w + c * 9;
  const float* src = lr + ((size_t)n * CD + c) * K;
  float s = 0.f;
#pragma unroll
  for (int dy = -1; dy <= 1; ++dy)
#pragma unroll
    for (int dx = -1; dx <= 1; ++dx) {
      int yy = y + dy, xx = x + dx;
      if (yy < 0 || yy >= LR || xx < 0 || xx >= LR) continue;
      s += src[yy * LR + xx] * wp[(dy + 1) * 3 + dx + 1];
    }
  x1[idx] = s / (1.f + expf(-s));
}

__global__ __launch_bounds__(256) void ln_c512(float* __restrict__ x,
                                               const float* __restrict__ w,
                                               const float* __restrict__ b) {
  const int n = blockIdx.x / 9;
  const int p0 = (blockIdx.x % 9) * 64;
  const int pl = threadIdx.x & 63;
  const int cg = threadIdx.x >> 6;
  float* base = x + (size_t)n * CD * K + p0 + pl;
  float s = 0.f, ss = 0.f;
  for (int c = cg * 128; c < cg * 128 + 128; ++c) {
    float v = base[(size_t)c * K];
    s += v; ss += v * v;
  }
  __shared__ float rs[4][64], rss[4][64];
  rs[cg][pl] = s; rss[cg][pl] = ss;
  __syncthreads();
  float S = rs[0][pl] + rs[1][pl] + rs[2][pl] + rs[3][pl];
  float SS = rss[0][pl] + rss[1][pl] + rss[2][pl] + rss[3][pl];
  const float mean = S * (1.f / CD);
  const float inv = rsqrtf(SS * (1.f / CD) - mean * mean + 1e-5f);
  for (int c = cg * 128; c < cg * 128 + 128; ++c) {
    float v = base[(size_t)c * K];
    base[(size_t)c * K] = (v - mean) * inv * w[c] + b[c];
  }
}

__global__ __launch_bounds__(576) void proj64(const float* __restrict__ x1,
                                              const float* __restrict__ w,
                                              float* __restrict__ x2) {
  const int n = blockIdx.x >> 3;
  const int o0 = (blockIdx.x & 7) * 8;
  const int p = threadIdx.x;
  const float* xb = x1 + (size_t)n * CD * K + p;
  float acc[8] = {0.f, 0.f, 0.f, 0.f, 0.f, 0.f, 0.f, 0.f};
  for (int c = 0; c < CD; ++c) {
    float v = xb[(size_t)c * K];
#pragma unroll
    for (int j = 0; j < 8; ++j) acc[j] += v * w[(o0 + j) * CD + c];
  }
#pragma unroll
  for (int j = 0; j < 8; ++j)
    x2[((size_t)n * INTER + o0 + j) * K + p] = acc[j];
}

__global__ __launch_bounds__(64) void gate_k(const float* __restrict__ pooled,
                                             const float* __restrict__ w,
                                             const float* __restrict__ bias,
                                             float* __restrict__ gate) {
  int idx = blockIdx.x * 64 + threadIdx.x;
  if (idx >= B * G * INTER) return;
  int n = idx >> 6, o = idx & 63;
  const float* pb = pooled + n * CD;
  const float* wb = w + o * CD;
  float s = bias[o];
  for (int c = 0; c < CD; ++c) s += pb[c] * wb[c];
  gate[idx] = 1.f / (1.f + expf(-s));
}

__global__ __launch_bounds__(256) void ln2_off_pos(
    const float* __restrict__ x2, const float* __restrict__ gate,
    const float* __restrict__ ln2w, const float* __restrict__ ln2b,
    const float* __restrict__ offw, float* __restrict__ pos) {
  int wid = (blockIdx.x * 256 + threadIdx.x) >> 6;
  int lane = threadIdx.x & 63;
  if (wid >= B * G * K) return;
  int n = wid / K, p = wid % K;
  float v = x2[((size_t)n * INTER + lane) * K + p] * gate[n * INTER + lane];
  float s = v, ss = v * v;
  for (int o = 32; o; o >>= 1) {
    s += __shfl_xor(s, o);
    ss += __shfl_xor(ss, o);
  }
  float mean = s * (1.f / INTER);
  float var = ss * (1.f / INTER) - mean * mean;
  float xn = (v - mean) * rsqrtf(var + 1e-5f) * ln2w[lane] + ln2b[lane];
  float ox = xn * offw[lane];
  float oy = xn * offw[INTER + lane];
  for (int o = 32; o; o >>= 1) {
    ox += __shfl_xor(ox, o);
    oy += __shfl_xor(oy, o);
  }
  if (lane == 0) {
    int yi = p / LR, xi = p % LR;
    float rx = (xi + 0.5f) / 23.f * 2.f - 1.f;
    float ry = (yi + 0.5f) / 23.f * 2.f - 1.f;
    pos[((size_t)n * K + p) * 2 + 0] = tanhf(rx + ox);
    pos[((size_t)n * K + p) * 2 + 1] = tanhf(ry + oy);
  }
}

__global__ __launch_bounds__(256) void sample_k(const float* __restrict__ img,
                                                const float* __restrict__ pos,
                                                u16* __restrict__ samp) {
  const int bk = blockIdx.x;
  const int b = bk / K, k = bk % K;
  __shared__ int s_idx[G][4];
  __shared__ float s_w[G][4];
  if (threadIdx.x < G) {
    int g = threadIdx.x;
    int n = b * G + g;
    float px = pos[((size_t)n * K + k) * 2 + 0];
    float py = pos[((size_t)n * K + k) * 2 + 1];
    float x = (px + 1.f) * 0.5f * (HR - 1);
    float y = (py + 1.f) * 0.5f * (HR - 1);
    float x0f = floorf(x), y0f = floorf(y);
    float wx = x - x0f, wy = y - y0f;
    int x0 = min(max((int)x0f, 0), HR - 1);
    int x1 = min(x0 + 1, HR - 1);
    int y0 = min(max((int)y0f, 0), HR - 1);
    int y1 = min(y0 + 1, HR - 1);
    s_idx[g][0] = y0 * HR + x0;
    s_idx[g][1] = y0 * HR + x1;
    s_idx[g][2] = y1 * HR + x0;
    s_idx[g][3] = y1 * HR + x1;
    s_w[g][0] = (1.f - wx) * (1.f - wy);
    s_w[g][1] = wx * (1.f - wy);
    s_w[g][2] = (1.f - wx) * wy;
    s_w[g][3] = wx * wy;
  }
  __syncthreads();
  const float* ib = img + (size_t)b * HR * HR * C;
  u16* ob = samp + ((size_t)b * K + k) * C;
  for (int ch = threadIdx.x; ch < C; ch += 256) {
    int g = ch >> 9;
    float v = s_w[g][0] * ib[(size_t)s_idx[g][0] * C + ch] +
              s_w[g][1] * ib[(size_t)s_idx[g][1] * C + ch] +
              s_w[g][2] * ib[(size_t)s_idx[g][2] * C + ch] +
              s_w[g][3] * ib[(size_t)s_idx[g][3] * C + ch];
    ob[ch] = f2bf1(v);
  }
}

// ---------------- KV-split MFMA flash attention (partials) ------------------
__global__ __launch_bounds__(256) void attn_part(
    const u16* __restrict__ qb, const u16* __restrict__ kg,
    const u16* __restrict__ vg, float* __restrict__ oA,
    float* __restrict__ oB, float* __restrict__ mlA,
    float* __restrict__ mlB) {
  const int i = blockIdx.x;
  const int fam = i >> 9;
  const int r9 = i & 511;
  int bh, qblk;
  if (fam == 0) {
    const int pair = r9 & 255, half = r9 >> 8;
    bh = pair & 31;
    const int q8 = pair >> 5;
    qblk = half ? (15 - q8) : q8;
  } else {
    bh = r9 & 31;
    qblk = r9 >> 5;
  }
  const int b = bh >> 4, h = bh & 15;
  const int q0 = qblk * 64;
  const int tid = threadIdx.x, lane = tid & 63, w = tid >> 6;
  const int qw = q0 + w * 16;
  const int col = lane & 15, kpart = lane >> 4, rbase = kpart * 4;
  __shared__ u16 Ks[2][4096];
  __shared__ u16 Vs[2][4096];
  __shared__ u16 Pl[4][16 * 40];
  float* oacc = fam ? oB : oA;
  float* ml = fam ? mlB : mlA;
  bf8 qf[4];
  {
    const u16* qp =
        qb + (size_t)(b * 1024 + qw + col) * 2048 + h * 128 + kpart * 8;
#pragma unroll
    for (int dc = 0; dc < 4; ++dc) qf[dc] = *(const bf8*)(qp + dc * 32);
  }
  f4 o[8];
#pragma unroll
  for (int df = 0; df < 8; ++df) o[df] = f4{0.f, 0.f, 0.f, 0.f};
  float m_r[4] = {-1e30f, -1e30f, -1e30f, -1e30f};
  float l_p[4] = {0.f, 0.f, 0.f, 0.f};  // per-lane partial (deferred reduce)
  const float scale = 0.08838834764831845f;
  const int nt = fam ? 18 : ((q0 + 64) >> 5);
  const int kvadd = fam ? 1024 : 0;
  const u16* kbh = kg + (size_t)bh * (NKV * 128);
  const u16* vbh = vg + (size_t)bh * (NKV * 128);
  u16* pw = &Pl[w][0];

#define ASTAGE(bi, kv0)                                                       \
  do {                                                                        \
    const u16* gk = kbh + (size_t)((kv0) >> 5) * 4096 + w * 1024 + lane * 8;  \
    GLDS(gk, &Ks[bi][w * 1024 + lane * 8]);                                   \
    GLDS(gk + 512, &Ks[bi][w * 1024 + 512 + lane * 8]);                       \
    const u16* gv = vbh + (size_t)((kv0) >> 3) * 1024 + w * 1024 + lane * 8;  \
    GLDS(gv, &Vs[bi][w * 1024 + lane * 8]);                                   \
    GLDS(gv + 512, &Vs[bi][w * 1024 + 512 + lane * 8]);                       \
  } while (0)

  ASTAGE(0, kvadd);
  int cur = 0;
  for (int t = 0; t < nt; ++t) {
    const int kv0 = kvadd + (t << 5);
    __syncthreads();
    if (t + 1 < nt) ASTAGE(cur ^ 1, kvadd + ((t + 1) << 5));
    const u16* ksb = &Ks[cur][0];
    const u16* vsb = &Vs[cur][0];
    f4 s0 = {0.f, 0.f, 0.f, 0.f}, s1 = {0.f, 0.f, 0.f, 0.f};
    __builtin_amdgcn_s_setprio(1);
#pragma unroll
    for (int dc = 0; dc < 4; ++dc) {
      const int dblk = dc * 4 + kpart;
      bf8 k0f = *(const bf8*)(ksb + (dblk * 32 + col) * 8);
      bf8 k1f = *(const bf8*)(ksb + (dblk * 32 + 16 + col) * 8);
      s0 = MFMA16(qf[dc], k0f, s0);
      s1 = MFMA16(qf[dc], k1f, s1);
    }
    __builtin_amdgcn_s_setprio(0);
    float sa[4], sc[4], loc[4], p0[4], p1[4];
    bool grow = false;
    const bool need_mask = (fam == 0) && (kv0 + 31 > qw);
#pragma unroll
    for (int rr = 0; rr < 4; ++rr) {
      float a = s0[rr] * scale, c2 = s1[rr] * scale;
      if (need_mask) {
        const int qg = qw + rbase + rr;
        if (kv0 + col > qg) a = -1e30f;
        if (kv0 + 16 + col > qg) c2 = -1e30f;
      }
      sa[rr] = a; sc[rr] = c2;
      loc[rr] = fmaxf(a, c2);
      grow |= (loc[rr] > m_r[rr] + 8.f);
    }
    if (__any(grow)) {  // rare: full rescale with max reduction
      float fr[4];
#pragma unroll
      for (int rr = 0; rr < 4; ++rr) {
        float mx = loc[rr];
        mx = fmaxf(mx, __shfl_xor(mx, 1));
        mx = fmaxf(mx, __shfl_xor(mx, 2));
        mx = fmaxf(mx, __shfl_xor(mx, 4));
        mx = fmaxf(mx, __shfl_xor(mx, 8));
        const float mn = fmaxf(m_r[rr], mx);
        fr[rr] = __expf(m_r[rr] - mn);
        m_r[rr] = mn;
        p0[rr] = __expf(sa[rr] - mn);
        p1[rr] = __expf(sc[rr] - mn);
        l_p[rr] = l_p[rr] * fr[rr] + p0[rr] + p1[rr];
      }
#pragma unroll
      for (int df = 0; df < 8; ++df) {
        o[df][0] *= fr[0]; o[df][1] *= fr[1];
        o[df][2] *= fr[2]; o[df][3] *= fr[3];
      }
    } else {  // steady state: no cross-lane ops at all
#pragma unroll
      for (int rr = 0; rr < 4; ++rr) {
        p0[rr] = __expf(sa[rr] - m_r[rr]);
        p1[rr] = __expf(sc[rr] - m_r[rr]);
        l_p[rr] += p0[rr] + p1[rr];
      }
    }
#pragma unroll
    for (int rr = 0; rr < 4; ++rr) {
      pw[(rbase + rr) * 40 + col] = f2bf1(p0[rr]);
      pw[(rbase + rr) * 40 + 16 + col] = f2bf1(p1[rr]);
    }
    bf8 pa = *(const bf8*)(pw + col * 40 + kpart * 8);
    __builtin_amdgcn_s_setprio(1);
#pragma unroll
    for (int df = 0; df < 8; ++df) {
      bf8 vf = *(const bf8*)(vsb + (kpart * 128 + df * 16 + col) * 8);
      o[df] = MFMA16(pa, vf, o[df]);
    }
    __builtin_amdgcn_s_setprio(0);
    cur ^= 1;
  }
#undef ASTAGE
  float l_r[4];
#pragma unroll
  for (int rr = 0; rr < 4; ++rr) {  // deferred cross-lane sum, once
    float ps = l_p[rr];
    ps += __shfl_xor(ps, 1);
    ps += __shfl_xor(ps, 2);
    ps += __shfl_xor(ps, 4);
    ps += __shfl_xor(ps, 8);
    l_r[rr] = ps;
  }
  float* orow = oacc + (size_t)(bh * 1024 + qw + rbase) * 128 + col;
#pragma unroll
  for (int df = 0; df < 8; ++df)
#pragma unroll
    for (int rr = 0; rr < 4; ++rr)
      orow[(size_t)rr * 128 + df * 16] = o[df][rr];
  if (col == 0) {
#pragma unroll
    for (int rr = 0; rr < 4; ++rr) {
      const int row = bh * 1024 + qw + rbase + rr;
      ml[row * 2] = m_r[rr];
      ml[row * 2 + 1] = l_r[rr];
    }
  }
}

__global__ __launch_bounds__(256) void attn_merge(
    const float* __restrict__ oA, const float* __restrict__ mlA,
    const float* __restrict__ oB, const float* __restrict__ mlB,
    u16* __restrict__ aob) {
  const int gid = blockIdx.x * 256 + threadIdx.x;
  const int row = gid >> 5;
  const int d0 = (gid & 31) * 4;
  const float mA = mlA[row * 2], lA = mlA[row * 2 + 1];
  const float mB = mlB[row * 2], lB = mlB[row * 2 + 1];
  const float m = fmaxf(mA, mB);
  const float wA = __expf(mA - m), wB = __expf(mB - m);
  const float inv = 1.f / (lA * wA + lB * wB);
  const f4 a = *(const f4*)(oA + (size_t)row * 128 + d0);
  const f4 c = *(const f4*)(oB + (size_t)row * 128 + d0);
  const int bh = row >> 10, q = row & 1023;
  const int bb = bh >> 4, h = bh & 15;
  u16* dst = aob + (size_t)(bb * 1024 + q) * 2048 + h * 128 + d0;
#pragma unroll
  for (int j = 0; j < 4; ++j)
    dst[j] = f2bf1((a[j] * wA + c[j] * wB) * inv);
}

// ---------------------------------------------------------------------------
extern "C" void kernel_launch(void* const* d_in, const int* in_sizes, int n_in,
                              void* d_out, int out_size, void* d_ws,
                              size_t ws_size, hipStream_t stream) {
  const float* hs = (const float*)d_in[0];
  const float* img = (const float*)d_in[1];
  const float* wq = (const float*)d_in[2];
  const float* wk = (const float*)d_in[3];
  const float* wv = (const float*)d_in[4];
  const float* wo = (const float*)d_in[5];
  const float* cdw = (const float*)d_in[6];
  const float* ln1w = (const float*)d_in[7];
  const float* ln1b = (const float*)d_in[8];
  const float* plrw = (const float*)d_in[9];
  const float* piw = (const float*)d_in[10];
  const float* pib = (const float*)d_in[11];
  const float* ln2w = (const float*)d_in[12];
  const float* ln2b = (const float*)d_in[13];
  const float* offw = (const float*)d_in[14];
  const float* khw = (const float*)d_in[15];
  const float* khb = (const float*)d_in[16];
  const float* vhw = (const float*)d_in[17];
  const float* vhb = (const float*)d_in[18];
  float* outp = (float*)d_out;

  u16* wsp = (u16*)d_ws;
  const size_t SZ = 4194304;  // 2048*2048
  u16* hs_st = wsp;            // staged
  u16* wq_st = wsp + SZ;       // staged; reused as aob_bf after gemm
  u16* wk_st = wsp + 2 * SZ;   // staged; oA overlay after gemm
  u16* wv_st = wsp + 3 * SZ;   // staged; oA overlay after gemm
  u16* wo_bf = wsp + 4 * SZ;   // row-major (live until gemm_out)
  u16* khw_bf = wsp + 5 * SZ;  // row-major; oB overlay after gemm
  u16* vhw_bf = wsp + 6 * SZ;  // row-major; oB overlay after gemm
  u16* qb_bf = wsp + 7 * SZ;
  u16* samp_bf = wsp + 8 * SZ;       // 1152*2048 row-major
  u16* kg = wsp + 8 * SZ + 2359296;  // 2*16*1600*128
  u16* vg = kg + 6553600;
  float* lrb = (float*)kg;  // fp32 scratch overlaps kg/vg (dead before gemms)
  float* x1b = lrb + 2359296;
  float* x2b = x1b + 2359296;
  float* poolb = x2b + 294912;
  float* gb = poolb + 4096;
  float* posb = (float*)(vg + 6553600);  // 9216 floats
  float* mlA = posb + 9216;              // 65536 floats
  float* mlB = mlA + 65536;              // 65536 floats
  float* oA = (float*)(wsp + 2 * SZ);    // 4M floats over wk_st+wv_st
  float* oB = (float*)(wsp + 5 * SZ);    // 4M floats over khw_bf+vhw_bf
  u16* aob_bf = wq_st;

  dim3 blk(256);
  // ---- offset network ----
  build_lr_t<<<dim3(1152), blk, 0, stream>>>(hs, lrb);
  pool_lr<<<dim3((B * G * CD) / 4), blk, 0, stream>>>(lrb, poolb);
  dwconv_silu<<<dim3((B * G * CD * K) / 256), blk, 0, stream>>>(lrb, cdw, x1b);
  ln_c512<<<dim3(B * G * 9), blk, 0, stream>>>(x1b, ln1w, ln1b);
  proj64<<<dim3(B * G * 8), dim3(576), 0, stream>>>(x1b, plrw, x2b);
  gate_k<<<dim3((B * G * INTER) / 64), dim3(64), 0, stream>>>(poolb, piw, pib,
                                                              gb);
  ln2_off_pos<<<dim3((B * G * K) / 4), blk, 0, stream>>>(x2b, gb, ln2w, ln2b,
                                                         offw, posb);
  sample_k<<<dim3(B * K), blk, 0, stream>>>(img, posb, samp_bf);

  // ---- bf16 conversions ----
  f2bf_k7<<<dim3(1024, 7), blk, 0, stream>>>(hs, wq, wk, wv, wo, khw, vhw,
                                             hs_st, wq_st, wk_st, wv_st,
                                             wo_bf, khw_bf, vhw_bf);

  // ---- fused MFMA GEMM: QKV (256^2 8-phase) + HD k/v (dual 128^2) ----
  gemm_fused<<<dim3(336), dim3(512), 0, stream>>>(
      hs_st, wq_st, wk_st, wv_st, samp_bf, khw_bf, vhw_bf, khb, vhb, qb_bf,
      kg, vg);
  // ---- attention (KV-split partials + merge) ----
  attn_part<<<dim3(1024), blk, 0, stream>>>(qb_bf, kg, vg, oA, oB, mlA, mlB);
  attn_merge<<<dim3(4096), blk, 0, stream>>>(oA, mlA, oB, mlB, aob_bf);
  // ---- output projection ----
  gemm_out<<<dim3(16, 16), blk, 0, stream>>>(aob_bf, wo_bf, outp);
}

// Round 7
// 367.766 us; speedup vs baseline: 1.1993x; 1.0000x over previous
//
#include <hip/hip_runtime.h>

typedef unsigned short u16;
typedef unsigned int u32;
typedef __attribute__((ext_vector_type(8))) short bf8;
typedef __attribute__((ext_vector_type(4))) float f4;
typedef __attribute__((ext_vector_type(4))) unsigned short us4;

constexpr int B = 2;
constexpr int NQ = 1024;
constexpr int C = 2048;
constexpr int DH = 128;
constexpr int G = 4;
constexpr int CD = 512;
constexpr int LR = 24;
constexpr int HR = 72;
constexpr int INTER = 64;
constexpr int K = LR * LR;  // 576
constexpr int NKV = NQ + K; // 1600

#define MFMA16(a, b, c) __builtin_amdgcn_mfma_f32_16x16x32_bf16(a, b, c, 0, 0, 0)
#define GLDS(g, l)                                                         \
  __builtin_amdgcn_global_load_lds(                                        \
      (const __attribute__((address_space(1))) void*)(g),                  \
      (__attribute__((address_space(3))) void*)(l), 16, 0, 0)

__device__ __forceinline__ u16 f2bf1(float f) {
  u32 u = __float_as_uint(f);
  u32 r = (u + 0x7fffu + ((u >> 16) & 1u)) >> 16;
  return (u16)r;
}

// ------------- fused fp32 -> bf16 (7 tensors) + plrw transpose --------------
// y<5: STAGED layout via LDS transpose (hs, wq, wk, wv, wo).
// y=5,6: row-major bf16 (khw, vhw). y=7: plrw [64][512] -> wt [512][64] fp32.
__global__ __launch_bounds__(256) void f2bf_k8(
    const float* __restrict__ s0, const float* __restrict__ s1,
    const float* __restrict__ s2, const float* __restrict__ s3,
    const float* __restrict__ s4, const float* __restrict__ s5,
    const float* __restrict__ s6, const float* __restrict__ plrw,
    u16* __restrict__ d0, u16* __restrict__ d1, u16* __restrict__ d2,
    u16* __restrict__ d3, u16* __restrict__ d4, u16* __restrict__ d5,
    u16* __restrict__ d6, float* __restrict__ wt) {
  __shared__ u16 L[64][68];
  const int y = blockIdx.y;
  const int t = threadIdx.x;
  if (y == 7) {
    if (blockIdx.x >= 128) return;
    const int idx = blockIdx.x * 256 + t;  // < 32768
    wt[idx] = plrw[(idx & 63) * 512 + (idx >> 6)];
    return;
  }
  const float* s;
  u16* d;
  switch (y) {
    case 0: s = s0; d = d0; break;
    case 1: s = s1; d = d1; break;
    case 2: s = s2; d = d2; break;
    case 3: s = s3; d = d3; break;
    case 4: s = s4; d = d4; break;
    case 5: s = s5; d = d5; break;
    default: s = s6; d = d6; break;
  }
  if (y < 5) {
    const int pc = blockIdx.x;  // piece 0..1023
    const int mb = pc >> 5, kb = pc & 31;
    const int rin = t >> 2, c0 = (t & 3) * 16;
    const float* src = s + (size_t)(mb * 64 + rin) * 2048 + kb * 64 + c0;
#pragma unroll
    for (int j = 0; j < 16; j += 4) {
      float4 v = *(const float4*)(src + j);
      L[rin][c0 + j] = f2bf1(v.x);
      L[rin][c0 + j + 1] = f2bf1(v.y);
      L[rin][c0 + j + 2] = f2bf1(v.z);
      L[rin][c0 + j + 3] = f2bf1(v.w);
    }
    __syncthreads();
    u16* dst = d + (size_t)pc * 4096 + t * 16;
#pragma unroll
    for (int gg = 0; gg < 2; ++gg) {
      const int g = t * 2 + gg;
      const int rh = g & 15, ks2 = (g >> 4) & 3, kc = (g >> 6) & 1, fr = g >> 7;
      const int row = fr * 16 + rh, cc = kc * 32 + ks2 * 8;
      us4 o0, o1;
      o0.x = L[row][cc];     o0.y = L[row][cc + 1];
      o0.z = L[row][cc + 2]; o0.w = L[row][cc + 3];
      o1.x = L[row][cc + 4]; o1.y = L[row][cc + 5];
      o1.z = L[row][cc + 6]; o1.w = L[row][cc + 7];
      *(us4*)(dst + gg * 8) = o0;
      *(us4*)(dst + gg * 8 + 4) = o1;
    }
  } else {
    const size_t i0 = ((size_t)blockIdx.x * 256 + t) * 16;
#pragma unroll
    for (int j = 0; j < 16; j += 4) {
      float4 v = *(const float4*)(s + i0 + j);
      us4 o;
      o.x = f2bf1(v.x); o.y = f2bf1(v.y); o.z = f2bf1(v.z); o.w = f2bf1(v.w);
      *(us4*)(d + i0 + j) = o;
    }
  }
}

// --------- fused GEMM: blocks 0-191 = QKV 256x256 8-phase (staged);
// --------- blocks 192-335 = HD k/v dual-128x128 m97 path (row-major samp).
#define SB()                               \
  do {                                     \
    __builtin_amdgcn_sched_barrier(0);     \
    __builtin_amdgcn_s_barrier();          \
    __builtin_amdgcn_sched_barrier(0);     \
  } while (0)
#define WVM(n) asm volatile("s_waitcnt vmcnt(" #n ")" ::: "memory")

__global__ __launch_bounds__(512, 2) void gemm_fused(
    const u16* __restrict__ Ast, const u16* __restrict__ Wq,
    const u16* __restrict__ Wk, const u16* __restrict__ Wv,
    const u16* __restrict__ samp, const u16* __restrict__ khw,
    const u16* __restrict__ vhw, const float* __restrict__ khb,
    const float* __restrict__ vhb, u16* __restrict__ outq,
    u16* __restrict__ kg, u16* __restrict__ vg) {
  __shared__ u16 As[2][4][4096];
  __shared__ u16 Bs[2][4][4096];
  const int tid = threadIdx.x, lane = tid & 63, w = tid >> 6;
  const int ks = lane >> 4, r = lane & 15;
  const int bid = blockIdx.x;

  if (bid < 192) {
    const int wm = w >> 2, wn = w & 3;
    const int swz = (bid & 7) * 24 + (bid >> 3);
    const int mt = swz / 24, nt = swz % 24;
    const u16* Wst = (nt < 8) ? Wq : (nt < 16) ? Wk : Wv;
    const int nb0 = (nt & 7) * 4;
    const int mb0 = mt * 4;

#define ST_A03(bi, kt)                                                        \
  do {                                                                        \
    GLDS(Ast + ((size_t)(mb0 + 0) * 32 + (kt)) * 4096 + tid * 8,              \
         &As[bi][0][tid * 8]);                                                \
    GLDS(Ast + ((size_t)(mb0 + 2) * 32 + (kt)) * 4096 + tid * 8,              \
         &As[bi][2][tid * 8]);                                                \
  } while (0)
#define ST_A47(bi, kt)                                                        \
  do {                                                                        \
    GLDS(Ast + ((size_t)(mb0 + 1) * 32 + (kt)) * 4096 + tid * 8,              \
         &As[bi][1][tid * 8]);                                                \
    GLDS(Ast + ((size_t)(mb0 + 3) * 32 + (kt)) * 4096 + tid * 8,              \
         &As[bi][3][tid * 8]);                                                \
  } while (0)
#define ST_B01(bi, kt)                                                        \
  do {                                                                        \
    GLDS(Wst + ((size_t)(nb0 + 0) * 32 + (kt)) * 4096 + tid * 8,              \
         &Bs[bi][0][tid * 8]);                                                \
    GLDS(Wst + ((size_t)(nb0 + 1) * 32 + (kt)) * 4096 + tid * 8,              \
         &Bs[bi][1][tid * 8]);                                                \
  } while (0)
#define ST_B23(bi, kt)                                                        \
  do {                                                                        \
    GLDS(Wst + ((size_t)(nb0 + 2) * 32 + (kt)) * 4096 + tid * 8,              \
         &Bs[bi][2][tid * 8]);                                                \
    GLDS(Wst + ((size_t)(nb0 + 3) * 32 + (kt)) * 4096 + tid * 8,              \
         &Bs[bi][3][tid * 8]);                                                \
  } while (0)
#define RD_A(dst, bi, half, kc)                                               \
  _Pragma("unroll") for (int i2 = 0; i2 < 4; ++i2) dst[i2] =                  \
      *(const bf8*)(&As[bi][wm * 2 + (half)]                                  \
                       [((i2 * 2 + (kc)) * 4 + ks) * 128 + r * 8]);
#define RD_B(dst, bi, kc)                                                     \
  _Pragma("unroll") for (int j2 = 0; j2 < 4; ++j2) dst[j2] =                  \
      *(const bf8*)(&Bs[bi][wn][((j2 * 2 + (kc)) * 4 + ks) * 128 + r * 8]);
#define MM(ACC, AF, BF)                                                       \
  do {                                                                        \
    __builtin_amdgcn_s_setprio(1);                                            \
    _Pragma("unroll") for (int i3 = 0; i3 < 4; ++i3)                          \
        _Pragma("unroll") for (int j3 = 0; j3 < 4; ++j3) ACC[i3][j3] =        \
            MFMA16(AF[i3], BF[j3], ACC[i3][j3]);                              \
    __builtin_amdgcn_s_setprio(0);                                            \
  } while (0)

    f4 accA[4][4], accB[4][4];
#pragma unroll
    for (int i = 0; i < 4; ++i)
#pragma unroll
      for (int j = 0; j < 4; ++j) {
        accA[i][j] = f4{0.f, 0.f, 0.f, 0.f};
        accB[i][j] = f4{0.f, 0.f, 0.f, 0.f};
      }
    bf8 af[4], b0[4], b1[4];

    ST_A03(0, 0); ST_B01(0, 0); ST_B23(0, 0); ST_A47(0, 0);
    ST_A03(1, 1); ST_B01(1, 1);
    WVM(6);
    SB();

    for (int t = 0; t < 32; ++t) {
      const int buf = t & 1;
      RD_A(af, buf, 0, 0);
      RD_B(b0, buf, 0);
      if (t + 1 < 32) ST_B23(buf ^ 1, t + 1);
      SB();
      MM(accA, af, b0);
      SB();
      RD_A(af, buf, 0, 1);
      RD_B(b1, buf, 1);
      if (t + 1 < 32) ST_A47(buf ^ 1, t + 1);
      SB();
      MM(accA, af, b1);
      if (t + 1 < 32) { WVM(8); } else { WVM(0); }
      SB();
      RD_A(af, buf, 1, 0);
      if (t + 2 < 32) ST_A03(buf, t + 2);
      SB();
      MM(accB, af, b0);
      SB();
      RD_A(af, buf, 1, 1);
      if (t + 2 < 32) ST_B01(buf, t + 2);
      SB();
      MM(accB, af, b1);
      if (t + 2 < 32) { WVM(6); } else if (t + 1 < 32) { WVM(2); }
      SB();
    }

#define EPI(ACC, HALF)                                                        \
  _Pragma("unroll") for (int i = 0; i < 4; ++i)                               \
      _Pragma("unroll") for (int j = 0; j < 4; ++j)                           \
          _Pragma("unroll") for (int rr = 0; rr < 4; ++rr) {                  \
    const int m = mt * 256 + wm * 128 + (HALF)*64 + i * 16 + ks * 4 + rr;     \
    const int n = nt * 256 + wn * 64 + j * 16 + r;                            \
    const float v = ACC[i][j][rr];                                            \
    const int sel = n >> 11, nn = n & 2047, hh = nn >> 7, dd = nn & 127;      \
    const int bb = m >> 10, qq = m & 1023;                                    \
    const u16 bv = f2bf1(v);                                                  \
    if (sel == 0) {                                                           \
      outq[(size_t)m * 2048 + nn] = bv;                                       \
    } else if (sel == 1) {                                                    \
      kg[(((size_t)(bb * 16 + hh) * 50 + (qq >> 5)) * 16 + (dd >> 3)) * 256 + \
         (qq & 31) * 8 + (dd & 7)] = bv;                                      \
    } else {                                                                  \
      vg[((size_t)(bb * 16 + hh) * 200 + (qq >> 3)) * 1024 + dd * 8 +         \
         (qq & 7)] = bv;                                                      \
    }                                                                         \
  }
    EPI(accA, 0)
    EPI(accB, 1)
#undef EPI
  } else {
    const int hb = bid - 192;  // 0..143
    const int mt = hb >> 4, nb = hb & 15;
    const int m0 = mt * 128, n0l = nb * 128;
    const int srow = lane >> 2, scol = (lane & 3) * 8;
    const int wh = w & 3;
    const int wr = wh >> 1, wc = wh & 1;
    const bool is_v = (w >= 4);
    const u16* Wp = is_v ? vhw : khw;
    const float* bias = is_v ? vhb : khb;

#define HDST(bi, k0)                                                          \
  do {                                                                        \
    GLDS(samp + (size_t)(m0 + w * 16 + srow) * 2048 + scol + (k0),            \
         &As[bi][0][w * 512 + lane * 8]);                                     \
    GLDS(Wp + (size_t)(n0l + wh * 32 + srow) * 2048 + scol + (k0),            \
         &Bs[bi][is_v ? 1 : 0][wh * 1024 + lane * 8]);                        \
    GLDS(Wp + (size_t)(n0l + wh * 32 + 16 + srow) * 2048 + scol + (k0),       \
         &Bs[bi][is_v ? 1 : 0][wh * 1024 + 512 + lane * 8]);                  \
  } while (0)

    f4 acc[4][4];
#pragma unroll
    for (int i = 0; i < 4; ++i)
#pragma unroll
      for (int j = 0; j < 4; ++j) acc[i][j] = f4{0.f, 0.f, 0.f, 0.f};
    const int koff = ks * 8;
    const int arow = wr * 64 + r, brow = wc * 64 + r;

    HDST(0, 0);
    int cur = 0;
    for (int k0 = 0; k0 < 2048; k0 += 32) {
      __syncthreads();
      if (k0 + 32 < 2048) HDST(cur ^ 1, k0 + 32);
      bf8 af2[4], bw[4];
#pragma unroll
      for (int i = 0; i < 4; ++i)
        af2[i] = *(const bf8*)(&As[cur][0][(arow + i * 16) * 32 + koff]);
#pragma unroll
      for (int j = 0; j < 4; ++j)
        bw[j] =
            *(const bf8*)(&Bs[cur][is_v ? 1 : 0][(brow + j * 16) * 32 + koff]);
#pragma unroll
      for (int i = 0; i < 4; ++i)
#pragma unroll
        for (int j = 0; j < 4; ++j)
          acc[i][j] = MFMA16(af2[i], bw[j], acc[i][j]);
      cur ^= 1;
    }
#undef HDST
    const int rbase = ks * 4;
#pragma unroll
    for (int i = 0; i < 4; ++i) {
#pragma unroll
      for (int j = 0; j < 4; ++j) {
        const int nn = n0l + wc * 64 + j * 16 + r;
        const int hh = nn >> 7, dd = nn & 127;
#pragma unroll
        for (int rr = 0; rr < 4; ++rr) {
          const int m = m0 + wr * 64 + i * 16 + rbase + rr;
          const int bb = m / 576;
          const int kv = 1024 + (m - bb * 576);
          const u16 bv = f2bf1(acc[i][j][rr] + bias[nn]);
          if (!is_v) {
            kg[(((size_t)(bb * 16 + hh) * 50 + (kv >> 5)) * 16 + (dd >> 3)) *
                   256 +
               (kv & 31) * 8 + (dd & 7)] = bv;
          } else {
            vg[((size_t)(bb * 16 + hh) * 200 + (kv >> 3)) * 1024 + dd * 8 +
               (kv & 7)] = bv;
          }
        }
      }
    }
  }
}

// --------- output projection: staged A (aob) x staged W (wo), 128^2 ---------
__global__ __launch_bounds__(256) void gemm_out_st(const u16* __restrict__ Ast2,
                                                   const u16* __restrict__ Wst,
                                                   float* __restrict__ outf) {
  __shared__ u16 As2[2][2][4096];
  __shared__ u16 Ws2[2][2][4096];
  const int tid = threadIdx.x, lane = tid & 63, w = tid >> 6;
  const int wr = w >> 1, wc = w & 1;
  const int ks = lane >> 4, r = lane & 15;
  const int mt = blockIdx.y, nt = blockIdx.x;

#define OST(bi, kt)                                                           \
  do {                                                                        \
    const size_t a0 = ((size_t)(mt * 2 + 0) * 32 + (kt)) * 4096;              \
    const size_t a1 = ((size_t)(mt * 2 + 1) * 32 + (kt)) * 4096;              \
    const size_t w0 = ((size_t)(nt * 2 + 0) * 32 + (kt)) * 4096;              \
    const size_t w1 = ((size_t)(nt * 2 + 1) * 32 + (kt)) * 4096;              \
    GLDS(Ast2 + a0 + tid * 8, &As2[bi][0][tid * 8]);                          \
    GLDS(Ast2 + a0 + 2048 + tid * 8, &As2[bi][0][2048 + tid * 8]);            \
    GLDS(Ast2 + a1 + tid * 8, &As2[bi][1][tid * 8]);                          \
    GLDS(Ast2 + a1 + 2048 + tid * 8, &As2[bi][1][2048 + tid * 8]);            \
    GLDS(Wst + w0 + tid * 8, &Ws2[bi][0][tid * 8]);                           \
    GLDS(Wst + w0 + 2048 + tid * 8, &Ws2[bi][0][2048 + tid * 8]);             \
    GLDS(Wst + w1 + tid * 8, &Ws2[bi][1][tid * 8]);                           \
    GLDS(Wst + w1 + 2048 + tid * 8, &Ws2[bi][1][2048 + tid * 8]);             \
  } while (0)

  f4 acc[4][4];
#pragma unroll
  for (int i = 0; i < 4; ++i)
#pragma unroll
    for (int j = 0; j < 4; ++j) acc[i][j] = f4{0.f, 0.f, 0.f, 0.f};

  OST(0, 0);
  int cur = 0;
  for (int kt = 0; kt < 32; ++kt) {
    __syncthreads();
    if (kt + 1 < 32) OST(cur ^ 1, kt + 1);
#pragma unroll
    for (int kc = 0; kc < 2; ++kc) {
      bf8 a_[4], b_[4];
#pragma unroll
      for (int i = 0; i < 4; ++i)
        a_[i] = *(const bf8*)(&As2[cur][wr][((i * 2 + kc) * 4 + ks) * 128 +
                                            r * 8]);
#pragma unroll
      for (int j = 0; j < 4; ++j)
        b_[j] = *(const bf8*)(&Ws2[cur][wc][((j * 2 + kc) * 4 + ks) * 128 +
                                            r * 8]);
#pragma unroll
      for (int i = 0; i < 4; ++i)
#pragma unroll
        for (int j = 0; j < 4; ++j)
          acc[i][j] = MFMA16(a_[i], b_[j], acc[i][j]);
    }
    cur ^= 1;
  }
#undef OST
#pragma unroll
  for (int i = 0; i < 4; ++i)
#pragma unroll
    for (int j = 0; j < 4; ++j) {
      const int n = nt * 128 + wc * 64 + j * 16 + r;
#pragma unroll
      for (int rr = 0; rr < 4; ++rr) {
        const int m = mt * 128 + wr * 64 + i * 16 + ks * 4 + rr;
        outf[(size_t)m * 2048 + n] = acc[i][j][rr];
      }
    }
}

// -------------- offset network: fused build+pool+dwconv+silu ----------------
// block = (n, cg): 32 channels x full 24x24 grid in LDS.
__global__ __launch_bounds__(256) void dwpool(const float* __restrict__ hs,
                                              const float* __restrict__ cw,
                                              float* __restrict__ x1,
                                              float* __restrict__ pooled) {
  __shared__ float L[32][577];
  const int bidx = blockIdx.x;  // n*16 + cg
  const int n = bidx >> 4, cg = bidx & 15;
  const int b = n >> 2, g = n & 3;
  const int c0 = cg * 32;
  const int t = threadIdx.x;
  {
    const int c = t & 31, pr = t >> 5;
    const float* src = hs + (size_t)b * 1024 * 2048 + g * 512 + c0 + c;
#pragma unroll 4
    for (int j = 0; j < 72; ++j) {
      const int p = j * 8 + pr;
      L[c][p] = src[(size_t)p * 2048];
    }
  }
  __syncthreads();
  {  // pool over raw values: 8 lanes per channel
    const int c = t >> 3, seg = t & 7;
    float s = 0.f;
    for (int i = 0; i < 72; ++i) s += L[c][seg * 72 + i];
    s += __shfl_xor(s, 1);
    s += __shfl_xor(s, 2);
    s += __shfl_xor(s, 4);
    if (seg == 0) pooled[n * 512 + c0 + c] = s * (1.f / 576.f);
  }
  // depthwise 3x3 + silu
  const size_t base_out = (size_t)(n * 512 + c0) * 576;
  for (int j = 0; j < 72; ++j) {
    const int idx = j * 256 + t;
    const int c = idx / 576, p = idx - c * 576;
    const int y = p / 24, x = p - y * 24;
    const float* wp = cw + (c0 + c) * 9;
    float s = 0.f;
#pragma unroll
    for (int dy = -1; dy <= 1; ++dy)
#pragma unroll
      for (int dx = -1; dx <= 1; ++dx) {
        const int yy = y + dy, xx = x + dx;
        if (yy < 0 || yy >= 24 || xx < 0 || xx >= 24) continue;
        s += L[c][yy * 24 + xx] * wp[(dy + 1) * 3 + dx + 1];
      }
    x1[base_out + idx] = s / (1.f + expf(-s));
  }
}

// -------------- offset network: fused LN(512) + 1x1 conv(->64) --------------
// block = (n, pc): 64 pixels, all 512 channels in LDS; wt = plrw^T [512][64].
__global__ __launch_bounds__(256) void lnproj(const float* __restrict__ x1,
                                              const float* __restrict__ ln1w,
                                              const float* __restrict__ ln1b,
                                              const float* __restrict__ wt,
                                              float* __restrict__ x2) {
  __shared__ float Xs[512][68];
  __shared__ float rs[4][64], rss[4][64];
  const int bidx = blockIdx.x;  // n*9 + pc
  const int n = bidx / 9, pc = bidx % 9;
  const int p0 = pc * 64;
  const int t = threadIdx.x;
  {  // load [512][64] slice, coalesced
    const int pl = t & 63, c4 = t >> 6;
    const float* src = x1 + (size_t)n * 512 * 576 + p0 + pl;
#pragma unroll 4
    for (int j = 0; j < 128; ++j) {
      const int c = j * 4 + c4;
      Xs[c][pl] = src[(size_t)c * 576];
    }
  }
  __syncthreads();
  {  // LayerNorm over channels, in-place
    const int pl = t & 63, q = t >> 6;
    float s = 0.f, ss = 0.f;
    for (int c = q * 128; c < q * 128 + 128; ++c) {
      const float v = Xs[c][pl];
      s += v;
      ss += v * v;
    }
    rs[q][pl] = s;
    rss[q][pl] = ss;
    __syncthreads();
    const float S = rs[0][pl] + rs[1][pl] + rs[2][pl] + rs[3][pl];
    const float SS = rss[0][pl] + rss[1][pl] + rss[2][pl] + rss[3][pl];
    const float mean = S * (1.f / 512.f);
    const float inv = rsqrtf(SS * (1.f / 512.f) - mean * mean + 1e-5f);
    for (int c = q * 128; c < q * 128 + 128; ++c)
      Xs[c][pl] = (Xs[c][pl] - mean) * inv * ln1w[c] + ln1b[c];
  }
  __syncthreads();
  {  // proj 512 -> 64: thread = 4 o x 4 pl register tile
    const int o4 = (t & 15) * 4, pl0 = (t >> 4) * 4;
    float acc[4][4] = {};
    for (int c = 0; c < 512; ++c) {
      const f4 xv = *(const f4*)(&Xs[c][pl0]);
      const f4 wv = *(const f4*)(&wt[c * 64 + o4]);
#pragma unroll
      for (int i = 0; i < 4; ++i)
#pragma unroll
        for (int j = 0; j < 4; ++j) acc[i][j] += wv[i] * xv[j];
    }
#pragma unroll
    for (int i = 0; i < 4; ++i) {
      f4 ov;
      ov[0] = acc[i][0]; ov[1] = acc[i][1];
      ov[2] = acc[i][2]; ov[3] = acc[i][3];
      *(f4*)(&x2[(size_t)(n * 64 + o4 + i) * 576 + p0 + pl0]) = ov;
    }
  }
}

__global__ __launch_bounds__(64) void gate_k(const float* __restrict__ pooled,
                                             const float* __restrict__ w,
                                             const float* __restrict__ bias,
                                             float* __restrict__ gate) {
  int idx = blockIdx.x * 64 + threadIdx.x;
  if (idx >= B * G * INTER) return;
  int n = idx >> 6, o = idx & 63;
  const float* pb = pooled + n * CD;
  const float* wb = w + o * CD;
  float s = bias[o];
  for (int c = 0; c < CD; ++c) s += pb[c] * wb[c];
  gate[idx] = 1.f / (1.f + expf(-s));
}

__global__ __launch_bounds__(256) void ln2_off_pos(
    const float* __restrict__ x2, const float* __restrict__ gate,
    const float* __restrict__ ln2w, const float* __restrict__ ln2b,
    const float* __restrict__ offw, float* __restrict__ pos) {
  int wid = (blockIdx.x * 256 + threadIdx.x) >> 6;
  int lane = threadIdx.x & 63;
  if (wid >= B * G * K) return;
  int n = wid / K, p = wid % K;
  float v = x2[((size_t)n * INTER + lane) * K + p] * gate[n * INTER + lane];
  float s = v, ss = v * v;
  for (int o = 32; o; o >>= 1) {
    s += __shfl_xor(s, o);
    ss += __shfl_xor(ss, o);
  }
  float mean = s * (1.f / INTER);
  float var = ss * (1.f / INTER) - mean * mean;
  float xn = (v - mean) * rsqrtf(var + 1e-5f) * ln2w[lane] + ln2b[lane];
  float ox = xn * offw[lane];
  float oy = xn * offw[INTER + lane];
  for (int o = 32; o; o >>= 1) {
    ox += __shfl_xor(ox, o);
    oy += __shfl_xor(oy, o);
  }
  if (lane == 0) {
    int yi = p / LR, xi = p % LR;
    float rx = (xi + 0.5f) / 23.f * 2.f - 1.f;
    float ry = (yi + 0.5f) / 23.f * 2.f - 1.f;
    pos[((size_t)n * K + p) * 2 + 0] = tanhf(rx + ox);
    pos[((size_t)n * K + p) * 2 + 1] = tanhf(ry + oy);
  }
}

__global__ __launch_bounds__(256) void sample_k(const float* __restrict__ img,
                                                const float* __restrict__ pos,
                                                u16* __restrict__ samp) {
  const int bk = blockIdx.x;
  const int b = bk / K, k = bk % K;
  __shared__ int s_idx[G][4];
  __shared__ float s_w[G][4];
  if (threadIdx.x < G) {
    int g = threadIdx.x;
    int n = b * G + g;
    float px = pos[((size_t)n * K + k) * 2 + 0];
    float py = pos[((size_t)n * K + k) * 2 + 1];
    float x = (px + 1.f) * 0.5f * (HR - 1);
    float y = (py + 1.f) * 0.5f * (HR - 1);
    float x0f = floorf(x), y0f = floorf(y);
    float wx = x - x0f, wy = y - y0f;
    int x0 = min(max((int)x0f, 0), HR - 1);
    int x1 = min(x0 + 1, HR - 1);
    int y0 = min(max((int)y0f, 0), HR - 1);
    int y1 = min(y0 + 1, HR - 1);
    s_idx[g][0] = y0 * HR + x0;
    s_idx[g][1] = y0 * HR + x1;
    s_idx[g][2] = y1 * HR + x0;
    s_idx[g][3] = y1 * HR + x1;
    s_w[g][0] = (1.f - wx) * (1.f - wy);
    s_w[g][1] = wx * (1.f - wy);
    s_w[g][2] = (1.f - wx) * wy;
    s_w[g][3] = wx * wy;
  }
  __syncthreads();
  const float* ib = img + (size_t)b * HR * HR * C;
  u16* ob = samp + ((size_t)b * K + k) * C;
  for (int ch = threadIdx.x; ch < C; ch += 256) {
    int g = ch >> 9;
    float v = s_w[g][0] * ib[(size_t)s_idx[g][0] * C + ch] +
              s_w[g][1] * ib[(size_t)s_idx[g][1] * C + ch] +
              s_w[g][2] * ib[(size_t)s_idx[g][2] * C + ch] +
              s_w[g][3] * ib[(size_t)s_idx[g][3] * C + ch];
    ob[ch] = f2bf1(v);
  }
}

// ---------------- KV-split MFMA flash attention (partials) ------------------
__global__ __launch_bounds__(256) void attn_part(
    const u16* __restrict__ qb, const u16* __restrict__ kg,
    const u16* __restrict__ vg, float* __restrict__ oA,
    float* __restrict__ oB, float* __restrict__ mlA,
    float* __restrict__ mlB) {
  const int i = blockIdx.x;
  const int fam = i >> 9;
  const int r9 = i & 511;
  int bh, qblk;
  if (fam == 0) {
    const int pair = r9 & 255, half = r9 >> 8;
    bh = pair & 31;
    const int q8 = pair >> 5;
    qblk = half ? (15 - q8) : q8;
  } else {
    bh = r9 & 31;
    qblk = r9 >> 5;
  }
  const int b = bh >> 4, h = bh & 15;
  const int q0 = qblk * 64;
  const int tid = threadIdx.x, lane = tid & 63, w = tid >> 6;
  const int qw = q0 + w * 16;
  const int col = lane & 15, kpart = lane >> 4, rbase = kpart * 4;
  __shared__ u16 Ks[2][4096];
  __shared__ u16 Vs[2][4096];
  __shared__ u16 Pl[4][16 * 40];
  float* oacc = fam ? oB : oA;
  float* ml = fam ? mlB : mlA;
  bf8 qf[4];
  {
    const u16* qp =
        qb + (size_t)(b * 1024 + qw + col) * 2048 + h * 128 + kpart * 8;
#pragma unroll
    for (int dc = 0; dc < 4; ++dc) qf[dc] = *(const bf8*)(qp + dc * 32);
  }
  f4 o[8];
#pragma unroll
  for (int df = 0; df < 8; ++df) o[df] = f4{0.f, 0.f, 0.f, 0.f};
  float m_r[4] = {-1e30f, -1e30f, -1e30f, -1e30f};
  float l_p[4] = {0.f, 0.f, 0.f, 0.f};
  const float scale = 0.08838834764831845f;
  const int nt = fam ? 18 : ((q0 + 64) >> 5);
  const int kvadd = fam ? 1024 : 0;
  const u16* kbh = kg + (size_t)bh * (NKV * 128);
  const u16* vbh = vg + (size_t)bh * (NKV * 128);
  u16* pw = &Pl[w][0];

#define ASTAGE(bi, kv0)                                                       \
  do {                                                                        \
    const u16* gk = kbh + (size_t)((kv0) >> 5) * 4096 + w * 1024 + lane * 8;  \
    GLDS(gk, &Ks[bi][w * 1024 + lane * 8]);                                   \
    GLDS(gk + 512, &Ks[bi][w * 1024 + 512 + lane * 8]);                       \
    const u16* gv = vbh + (size_t)((kv0) >> 3) * 1024 + w * 1024 + lane * 8;  \
    GLDS(gv, &Vs[bi][w * 1024 + lane * 8]);                                   \
    GLDS(gv + 512, &Vs[bi][w * 1024 + 512 + lane * 8]);                       \
  } while (0)

  ASTAGE(0, kvadd);
  int cur = 0;
  for (int t = 0; t < nt; ++t) {
    const int kv0 = kvadd + (t << 5);
    __syncthreads();
    if (t + 1 < nt) ASTAGE(cur ^ 1, kvadd + ((t + 1) << 5));
    const u16* ksb = &Ks[cur][0];
    const u16* vsb = &Vs[cur][0];
    f4 s0 = {0.f, 0.f, 0.f, 0.f}, s1 = {0.f, 0.f, 0.f, 0.f};
    __builtin_amdgcn_s_setprio(1);
#pragma unroll
    for (int dc = 0; dc < 4; ++dc) {
      const int dblk = dc * 4 + kpart;
      bf8 k0f = *(const bf8*)(ksb + (dblk * 32 + col) * 8);
      bf8 k1f = *(const bf8*)(ksb + (dblk * 32 + 16 + col) * 8);
      s0 = MFMA16(qf[dc], k0f, s0);
      s1 = MFMA16(qf[dc], k1f, s1);
    }
    __builtin_amdgcn_s_setprio(0);
    float sa[4], sc[4], loc[4], p0[4], p1[4];
    bool grow = false;
    const bool need_mask = (fam == 0) && (kv0 + 31 > qw);
#pragma unroll
    for (int rr = 0; rr < 4; ++rr) {
      float a = s0[rr] * scale, c2 = s1[rr] * scale;
      if (need_mask) {
        const int qg = qw + rbase + rr;
        if (kv0 + col > qg) a = -1e30f;
        if (kv0 + 16 + col > qg) c2 = -1e30f;
      }
      sa[rr] = a; sc[rr] = c2;
      loc[rr] = fmaxf(a, c2);
      grow |= (loc[rr] > m_r[rr] + 8.f);
    }
    if (__any(grow)) {
      float fr[4];
#pragma unroll
      for (int rr = 0; rr < 4; ++rr) {
        float mx = loc[rr];
        mx = fmaxf(mx, __shfl_xor(mx, 1));
        mx = fmaxf(mx, __shfl_xor(mx, 2));
        mx = fmaxf(mx, __shfl_xor(mx, 4));
        mx = fmaxf(mx, __shfl_xor(mx, 8));
        const float mn = fmaxf(m_r[rr], mx);
        fr[rr] = __expf(m_r[rr] - mn);
        m_r[rr] = mn;
        p0[rr] = __expf(sa[rr] - mn);
        p1[rr] = __expf(sc[rr] - mn);
        l_p[rr] = l_p[rr] * fr[rr] + p0[rr] + p1[rr];
      }
#pragma unroll
      for (int df = 0; df < 8; ++df) {
        o[df][0] *= fr[0]; o[df][1] *= fr[1];
        o[df][2] *= fr[2]; o[df][3] *= fr[3];
      }
    } else {
#pragma unroll
      for (int rr = 0; rr < 4; ++rr) {
        p0[rr] = __expf(sa[rr] - m_r[rr]);
        p1[rr] = __expf(sc[rr] - m_r[rr]);
        l_p[rr] += p0[rr] + p1[rr];
      }
    }
#pragma unroll
    for (int rr = 0; rr < 4; ++rr) {
      pw[(rbase + rr) * 40 + col] = f2bf1(p0[rr]);
      pw[(rbase + rr) * 40 + 16 + col] = f2bf1(p1[rr]);
    }
    bf8 pa = *(const bf8*)(pw + col * 40 + kpart * 8);
    __builtin_amdgcn_s_setprio(1);
#pragma unroll
    for (int df = 0; df < 8; ++df) {
      bf8 vf = *(const bf8*)(vsb + (kpart * 128 + df * 16 + col) * 8);
      o[df] = MFMA16(pa, vf, o[df]);
    }
    __builtin_amdgcn_s_setprio(0);
    cur ^= 1;
  }
#undef ASTAGE
  float l_r[4];
#pragma unroll
  for (int rr = 0; rr < 4; ++rr) {
    float ps = l_p[rr];
    ps += __shfl_xor(ps, 1);
    ps += __shfl_xor(ps, 2);
    ps += __shfl_xor(ps, 4);
    ps += __shfl_xor(ps, 8);
    l_r[rr] = ps;
  }
  float* orow = oacc + (size_t)(bh * 1024 + qw + rbase) * 128 + col;
#pragma unroll
  for (int df = 0; df < 8; ++df)
#pragma unroll
    for (int rr = 0; rr < 4; ++rr)
      orow[(size_t)rr * 128 + df * 16] = o[df][rr];
  if (col == 0) {
#pragma unroll
    for (int rr = 0; rr < 4; ++rr) {
      const int row = bh * 1024 + qw + rbase + rr;
      ml[row * 2] = m_r[rr];
      ml[row * 2 + 1] = l_r[rr];
    }
  }
}

// merge partials -> aob in STAGED layout (feeds gemm_out_st directly)
__global__ __launch_bounds__(256) void attn_merge(
    const float* __restrict__ oA, const float* __restrict__ mlA,
    const float* __restrict__ oB, const float* __restrict__ mlB,
    u16* __restrict__ aob_st) {
  const int gid = blockIdx.x * 256 + threadIdx.x;
  const int row = gid >> 5;
  const int d0 = (gid & 31) * 4;
  const float mA = mlA[row * 2], lA = mlA[row * 2 + 1];
  const float mB = mlB[row * 2], lB = mlB[row * 2 + 1];
  const float m = fmaxf(mA, mB);
  const float wA = __expf(mA - m), wB = __expf(mB - m);
  const float inv = 1.f / (lA * wA + lB * wB);
  const f4 a = *(const f4*)(oA + (size_t)row * 128 + d0);
  const f4 c = *(const f4*)(oB + (size_t)row * 128 + d0);
  const int bh = row >> 10, q = row & 1023;
  const int bb = bh >> 4, h = bh & 15;
  const int mm = bb * 1024 + q;
  const int col = h * 128 + d0;
  const int mb = mm >> 6, fr = (mm >> 4) & 3, r = mm & 15;
  const int kb = col >> 6, kc = (col >> 5) & 1, ks = (col >> 3) & 3,
            j0 = col & 7;
  u16* dst = aob_st + ((size_t)(mb * 32 + kb)) * 4096 +
             (((fr * 2 + kc) * 4 + ks) * 16 + r) * 8 + j0;
  us4 ov;
  ov.x = f2bf1((a[0] * wA + c[0] * wB) * inv);
  ov.y = f2bf1((a[1] * wA + c[1] * wB) * inv);
  ov.z = f2bf1((a[2] * wA + c[2] * wB) * inv);
  ov.w = f2bf1((a[3] * wA + c[3] * wB) * inv);
  *(us4*)dst = ov;
}

// ---------------------------------------------------------------------------
extern "C" void kernel_launch(void* const* d_in, const int* in_sizes, int n_in,
                              void* d_out, int out_size, void* d_ws,
                              size_t ws_size, hipStream_t stream) {
  const float* hs = (const float*)d_in[0];
  const float* img = (const float*)d_in[1];
  const float* wq = (const float*)d_in[2];
  const float* wk = (const float*)d_in[3];
  const float* wv = (const float*)d_in[4];
  const float* wo = (const float*)d_in[5];
  const float* cdw = (const float*)d_in[6];
  const float* ln1w = (const float*)d_in[7];
  const float* ln1b = (const float*)d_in[8];
  const float* plrw = (const float*)d_in[9];
  const float* piw = (const float*)d_in[10];
  const float* pib = (const float*)d_in[11];
  const float* ln2w = (const float*)d_in[12];
  const float* ln2b = (const float*)d_in[13];
  const float* offw = (const float*)d_in[14];
  const float* khw = (const float*)d_in[15];
  const float* khb = (const float*)d_in[16];
  const float* vhw = (const float*)d_in[17];
  const float* vhb = (const float*)d_in[18];
  float* outp = (float*)d_out;

  u16* wsp = (u16*)d_ws;
  const size_t SZ = 4194304;  // 2048*2048
  u16* hs_st = wsp;            // staged
  u16* wq_st = wsp + SZ;       // staged; reused as aob (staged) after gemm
  u16* wk_st = wsp + 2 * SZ;   // staged; oA overlay after gemm
  u16* wv_st = wsp + 3 * SZ;   // staged; oA overlay after gemm
  u16* wo_st = wsp + 4 * SZ;   // staged (live until gemm_out_st)
  u16* khw_bf = wsp + 5 * SZ;  // row-major; oB overlay after gemm
  u16* vhw_bf = wsp + 6 * SZ;  // row-major; oB overlay after gemm
  u16* qb_bf = wsp + 7 * SZ;
  u16* samp_bf = wsp + 8 * SZ;       // 1152*2048 row-major
  u16* kg = wsp + 8 * SZ + 2359296;  // 2*16*1600*128
  u16* vg = kg + 6553600;
  // fp32 scratch overlays kg/vg (dead before gemms)
  float* x1b = (float*)kg + 2359296;
  float* x2b = x1b + 2359296;
  float* poolb = x2b + 294912;
  float* gb = poolb + 4096;
  float* posb = (float*)(vg + 6553600);  // 9216 floats (after vg, persistent)
  float* mlA = posb + 9216;              // 65536 floats
  float* mlB = mlA + 65536;              // 65536 floats
  float* wtb = mlB + 65536;              // 32768 floats (plrw^T)
  float* oA = (float*)(wsp + 2 * SZ);    // 4M floats over wk_st+wv_st
  float* oB = (float*)(wsp + 5 * SZ);    // 4M floats over khw_bf+vhw_bf
  u16* aob_st = wq_st;

  dim3 blk(256);
  // ---- offset network (fused) ----
  dwpool<<<dim3(128), blk, 0, stream>>>(hs, cdw, x1b, poolb);
  // ---- bf16 conversions + plrw transpose ----
  f2bf_k8<<<dim3(1024, 8), blk, 0, stream>>>(hs, wq, wk, wv, wo, khw, vhw,
                                             plrw, hs_st, wq_st, wk_st, wv_st,
                                             wo_st, khw_bf, vhw_bf, wtb);
  lnproj<<<dim3(72), blk, 0, stream>>>(x1b, ln1w, ln1b, wtb, x2b);
  gate_k<<<dim3(8), dim3(64), 0, stream>>>(poolb, piw, pib, gb);
  ln2_off_pos<<<dim3(1152), blk, 0, stream>>>(x2b, gb, ln2w, ln2b, offw, posb);
  sample_k<<<dim3(B * K), blk, 0, stream>>>(img, posb, samp_bf);

  // ---- fused MFMA GEMM: QKV (256^2 8-phase) + HD k/v (dual 128^2) ----
  gemm_fused<<<dim3(336), dim3(512), 0, stream>>>(
      hs_st, wq_st, wk_st, wv_st, samp_bf, khw_bf, vhw_bf, khb, vhb, qb_bf,
      kg, vg);
  // ---- attention (KV-split partials + merge to staged aob) ----
  attn_part<<<dim3(1024), blk, 0, stream>>>(qb_bf, kg, vg, oA, oB, mlA, mlB);
  attn_merge<<<dim3(4096), blk, 0, stream>>>(oA, mlA, oB, mlB, aob_st);
  // ---- output projection (staged x staged) ----
  gemm_out_st<<<dim3(16, 16), blk, 0, stream>>>(aob_st, wo_st, outp);
}

// Round 8
// 346.132 us; speedup vs baseline: 1.2742x; 1.0625x over previous
//
#include <hip/hip_runtime.h>

typedef unsigned short u16;
typedef unsigned int u32;
typedef __attribute__((ext_vector_type(8))) short bf8;
typedef __attribute__((ext_vector_type(4))) float f4;
typedef __attribute__((ext_vector_type(4))) unsigned short us4;

constexpr int B = 2;
constexpr int NQ = 1024;
constexpr int C = 2048;
constexpr int DH = 128;
constexpr int G = 4;
constexpr int CD = 512;
constexpr int LR = 24;
constexpr int HR = 72;
constexpr int INTER = 64;
constexpr int K = LR * LR;  // 576
constexpr int NKV = NQ + K; // 1600

#define MFMA16(a, b, c) __builtin_amdgcn_mfma_f32_16x16x32_bf16(a, b, c, 0, 0, 0)
#define GLDS(g, l)                                                         \
  __builtin_amdgcn_global_load_lds(                                        \
      (const __attribute__((address_space(1))) void*)(g),                  \
      (__attribute__((address_space(3))) void*)(l), 16, 0, 0)
#define SB()                               \
  do {                                     \
    __builtin_amdgcn_sched_barrier(0);     \
    __builtin_amdgcn_s_barrier();          \
    __builtin_amdgcn_sched_barrier(0);     \
  } while (0)
#define WVM(n)                                              \
  do {                                                      \
    asm volatile("s_waitcnt vmcnt(" #n ")" ::: "memory");   \
    __builtin_amdgcn_sched_barrier(0);                      \
  } while (0)

__device__ __forceinline__ u16 f2bf1(float f) {
  u32 u = __float_as_uint(f);
  u32 r = (u + 0x7fffu + ((u >> 16) & 1u)) >> 16;
  return (u16)r;
}

// ---- fused launch 1: fp32->bf16 (7 tensors, staged/rowmajor) + plrw^T +
// ----                 dwconv/pool (independent offset-net head)
__global__ __launch_bounds__(256) void f2bf_k9(
    const float* __restrict__ s0, const float* __restrict__ s1,
    const float* __restrict__ s2, const float* __restrict__ s3,
    const float* __restrict__ s4, const float* __restrict__ s5,
    const float* __restrict__ s6, const float* __restrict__ plrw,
    const float* __restrict__ cdw, u16* __restrict__ d0, u16* __restrict__ d1,
    u16* __restrict__ d2, u16* __restrict__ d3, u16* __restrict__ d4,
    u16* __restrict__ d5, u16* __restrict__ d6, float* __restrict__ wt,
    float* __restrict__ x1, float* __restrict__ pooled) {
  __shared__ float SH[32 * 577];  // dwpool view; aliased u16[64][68] for f2bf
  const int y = blockIdx.y;
  const int t = threadIdx.x;
  if (y == 7) {  // plrw transpose
    if (blockIdx.x >= 128) return;
    const int idx = blockIdx.x * 256 + t;
    wt[idx] = plrw[(idx & 63) * 512 + (idx >> 6)];
    return;
  }
  if (y == 8) {  // dwconv3x3+silu+pool, 32ch x 24x24 grid per block
    if (blockIdx.x >= 128) return;
    const int n = blockIdx.x >> 4, cg = blockIdx.x & 15;
    const int b = n >> 2, g = n & 3;
    const int c0 = cg * 32;
    {
      const int c = t & 31, pr = t >> 5;
      const float* src = s0 + (size_t)b * 1024 * 2048 + g * 512 + c0 + c;
#pragma unroll 4
      for (int j = 0; j < 72; ++j) {
        const int p = j * 8 + pr;
        SH[c * 577 + p] = src[(size_t)p * 2048];
      }
    }
    __syncthreads();
    {
      const int c = t >> 3, seg = t & 7;
      float s = 0.f;
      for (int i = 0; i < 72; ++i) s += SH[c * 577 + seg * 72 + i];
      s += __shfl_xor(s, 1);
      s += __shfl_xor(s, 2);
      s += __shfl_xor(s, 4);
      if (seg == 0) pooled[n * 512 + c0 + c] = s * (1.f / 576.f);
    }
    const size_t base_out = (size_t)(n * 512 + c0) * 576;
    for (int j = 0; j < 72; ++j) {
      const int idx = j * 256 + t;
      const int c = idx / 576, p = idx - c * 576;
      const int yy0 = p / 24, xx0 = p - yy0 * 24;
      const float* wp = cdw + (c0 + c) * 9;
      float s = 0.f;
#pragma unroll
      for (int dy = -1; dy <= 1; ++dy)
#pragma unroll
        for (int dx = -1; dx <= 1; ++dx) {
          const int yy = yy0 + dy, xx = xx0 + dx;
          if (yy < 0 || yy >= 24 || xx < 0 || xx >= 24) continue;
          s += SH[c * 577 + yy * 24 + xx] * wp[(dy + 1) * 3 + dx + 1];
        }
      x1[base_out + idx] = s / (1.f + expf(-s));
    }
    return;
  }
  const float* s;
  u16* d;
  switch (y) {
    case 0: s = s0; d = d0; break;
    case 1: s = s1; d = d1; break;
    case 2: s = s2; d = d2; break;
    case 3: s = s3; d = d3; break;
    case 4: s = s4; d = d4; break;
    case 5: s = s5; d = d5; break;
    default: s = s6; d = d6; break;
  }
  if (y < 5) {  // staged layout via LDS transpose
    u16* L = (u16*)SH;  // [64][68]
    const int pc = blockIdx.x;
    const int mb = pc >> 5, kb = pc & 31;
    const int rin = t >> 2, c0 = (t & 3) * 16;
    const float* src = s + (size_t)(mb * 64 + rin) * 2048 + kb * 64 + c0;
#pragma unroll
    for (int j = 0; j < 16; j += 4) {
      float4 v = *(const float4*)(src + j);
      L[rin * 68 + c0 + j] = f2bf1(v.x);
      L[rin * 68 + c0 + j + 1] = f2bf1(v.y);
      L[rin * 68 + c0 + j + 2] = f2bf1(v.z);
      L[rin * 68 + c0 + j + 3] = f2bf1(v.w);
    }
    __syncthreads();
    u16* dst = d + (size_t)pc * 4096 + t * 16;
#pragma unroll
    for (int gg = 0; gg < 2; ++gg) {
      const int g = t * 2 + gg;
      const int rh = g & 15, ks2 = (g >> 4) & 3, kc = (g >> 6) & 1, fr = g >> 7;
      const int row = fr * 16 + rh, cc = kc * 32 + ks2 * 8;
      us4 o0, o1;
      o0.x = L[row * 68 + cc];     o0.y = L[row * 68 + cc + 1];
      o0.z = L[row * 68 + cc + 2]; o0.w = L[row * 68 + cc + 3];
      o1.x = L[row * 68 + cc + 4]; o1.y = L[row * 68 + cc + 5];
      o1.z = L[row * 68 + cc + 6]; o1.w = L[row * 68 + cc + 7];
      *(us4*)(dst + gg * 8) = o0;
      *(us4*)(dst + gg * 8 + 4) = o1;
    }
  } else {
    const size_t i0 = ((size_t)blockIdx.x * 256 + t) * 16;
#pragma unroll
    for (int j = 0; j < 16; j += 4) {
      float4 v = *(const float4*)(s + i0 + j);
      us4 o;
      o.x = f2bf1(v.x); o.y = f2bf1(v.y); o.z = f2bf1(v.z); o.w = f2bf1(v.w);
      *(us4*)(d + i0 + j) = o;
    }
  }
}

// --------- fused GEMM: blocks 0-191 = QKV 256x256 8-phase (staged);
// --------- blocks 192-335 = HD k/v dual-128x128, counted-vmcnt pipeline.
__global__ __launch_bounds__(512, 2) void gemm_fused(
    const u16* __restrict__ Ast, const u16* __restrict__ Wq,
    const u16* __restrict__ Wk, const u16* __restrict__ Wv,
    const u16* __restrict__ samp, const u16* __restrict__ khw,
    const u16* __restrict__ vhw, const float* __restrict__ khb,
    const float* __restrict__ vhb, u16* __restrict__ outq,
    u16* __restrict__ kg, u16* __restrict__ vg) {
  __shared__ u16 As[2][4][4096];
  __shared__ u16 Bs[2][4][4096];
  const int tid = threadIdx.x, lane = tid & 63, w = tid >> 6;
  const int ks = lane >> 4, r = lane & 15;
  const int bid = blockIdx.x;

  if (bid < 192) {
    const int wm = w >> 2, wn = w & 3;
    const int swz = (bid & 7) * 24 + (bid >> 3);
    const int mt = swz / 24, nt = swz % 24;
    const u16* Wst = (nt < 8) ? Wq : (nt < 16) ? Wk : Wv;
    const int nb0 = (nt & 7) * 4;
    const int mb0 = mt * 4;

#define ST_A03(bi, kt)                                                        \
  do {                                                                        \
    GLDS(Ast + ((size_t)(mb0 + 0) * 32 + (kt)) * 4096 + tid * 8,              \
         &As[bi][0][tid * 8]);                                                \
    GLDS(Ast + ((size_t)(mb0 + 2) * 32 + (kt)) * 4096 + tid * 8,              \
         &As[bi][2][tid * 8]);                                                \
  } while (0)
#define ST_A47(bi, kt)                                                        \
  do {                                                                        \
    GLDS(Ast + ((size_t)(mb0 + 1) * 32 + (kt)) * 4096 + tid * 8,              \
         &As[bi][1][tid * 8]);                                                \
    GLDS(Ast + ((size_t)(mb0 + 3) * 32 + (kt)) * 4096 + tid * 8,              \
         &As[bi][3][tid * 8]);                                                \
  } while (0)
#define ST_B01(bi, kt)                                                        \
  do {                                                                        \
    GLDS(Wst + ((size_t)(nb0 + 0) * 32 + (kt)) * 4096 + tid * 8,              \
         &Bs[bi][0][tid * 8]);                                                \
    GLDS(Wst + ((size_t)(nb0 + 1) * 32 + (kt)) * 4096 + tid * 8,              \
         &Bs[bi][1][tid * 8]);                                                \
  } while (0)
#define ST_B23(bi, kt)                                                        \
  do {                                                                        \
    GLDS(Wst + ((size_t)(nb0 + 2) * 32 + (kt)) * 4096 + tid * 8,              \
         &Bs[bi][2][tid * 8]);                                                \
    GLDS(Wst + ((size_t)(nb0 + 3) * 32 + (kt)) * 4096 + tid * 8,              \
         &Bs[bi][3][tid * 8]);                                                \
  } while (0)
#define RD_A(dst, bi, half, kc)                                               \
  _Pragma("unroll") for (int i2 = 0; i2 < 4; ++i2) dst[i2] =                  \
      *(const bf8*)(&As[bi][wm * 2 + (half)]                                  \
                       [((i2 * 2 + (kc)) * 4 + ks) * 128 + r * 8]);
#define RD_B(dst, bi, kc)                                                     \
  _Pragma("unroll") for (int j2 = 0; j2 < 4; ++j2) dst[j2] =                  \
      *(const bf8*)(&Bs[bi][wn][((j2 * 2 + (kc)) * 4 + ks) * 128 + r * 8]);
#define MM(ACC, AF, BF)                                                       \
  do {                                                                        \
    __builtin_amdgcn_s_setprio(1);                                            \
    _Pragma("unroll") for (int i3 = 0; i3 < 4; ++i3)                          \
        _Pragma("unroll") for (int j3 = 0; j3 < 4; ++j3) ACC[i3][j3] =        \
            MFMA16(AF[i3], BF[j3], ACC[i3][j3]);                              \
    __builtin_amdgcn_s_setprio(0);                                            \
  } while (0)

    f4 accA[4][4], accB[4][4];
#pragma unroll
    for (int i = 0; i < 4; ++i)
#pragma unroll
      for (int j = 0; j < 4; ++j) {
        accA[i][j] = f4{0.f, 0.f, 0.f, 0.f};
        accB[i][j] = f4{0.f, 0.f, 0.f, 0.f};
      }
    bf8 af[4], b0[4], b1[4];

    ST_A03(0, 0); ST_B01(0, 0); ST_B23(0, 0); ST_A47(0, 0);
    ST_A03(1, 1); ST_B01(1, 1);
    WVM(6);
    SB();

    for (int t = 0; t < 32; ++t) {
      const int buf = t & 1;
      RD_A(af, buf, 0, 0);
      RD_B(b0, buf, 0);
      if (t + 1 < 32) ST_B23(buf ^ 1, t + 1);
      SB();
      MM(accA, af, b0);
      SB();
      RD_A(af, buf, 0, 1);
      RD_B(b1, buf, 1);
      if (t + 1 < 32) ST_A47(buf ^ 1, t + 1);
      SB();
      MM(accA, af, b1);
      if (t + 1 < 32) { WVM(8); } else { WVM(0); }
      SB();
      RD_A(af, buf, 1, 0);
      if (t + 2 < 32) ST_A03(buf, t + 2);
      SB();
      MM(accB, af, b0);
      SB();
      RD_A(af, buf, 1, 1);
      if (t + 2 < 32) ST_B01(buf, t + 2);
      SB();
      MM(accB, af, b1);
      if (t + 2 < 32) { WVM(6); } else if (t + 1 < 32) { WVM(2); }
      SB();
    }

#define EPI(ACC, HALF)                                                        \
  _Pragma("unroll") for (int i = 0; i < 4; ++i)                               \
      _Pragma("unroll") for (int j = 0; j < 4; ++j)                           \
          _Pragma("unroll") for (int rr = 0; rr < 4; ++rr) {                  \
    const int m = mt * 256 + wm * 128 + (HALF)*64 + i * 16 + ks * 4 + rr;     \
    const int n = nt * 256 + wn * 64 + j * 16 + r;                            \
    const float v = ACC[i][j][rr];                                            \
    const int sel = n >> 11, nn = n & 2047, hh = nn >> 7, dd = nn & 127;      \
    const int bb = m >> 10, qq = m & 1023;                                    \
    const u16 bv = f2bf1(v);                                                  \
    if (sel == 0) {                                                           \
      outq[(size_t)m * 2048 + nn] = bv;                                       \
    } else if (sel == 1) {                                                    \
      kg[(((size_t)(bb * 16 + hh) * 50 + (qq >> 5)) * 16 + (dd >> 3)) * 256 + \
         (qq & 31) * 8 + (dd & 7)] = bv;                                      \
    } else {                                                                  \
      vg[((size_t)(bb * 16 + hh) * 200 + (qq >> 3)) * 1024 + dd * 8 +         \
         (qq & 7)] = bv;                                                      \
    }                                                                         \
  }
    EPI(accA, 0)
    EPI(accB, 1)
#undef EPI
  } else {
    const int hb = bid - 192;  // 0..143
    const int mt = hb >> 4, nb = hb & 15;
    const int m0 = mt * 128, n0l = nb * 128;
    const int srow = lane >> 2, scol = (lane & 3) * 8;
    const int wh = w & 3;
    const int wr = wh >> 1, wc = wh & 1;
    const bool is_v = (w >= 4);
    const u16* Wp = is_v ? vhw : khw;
    const float* bias = is_v ? vhb : khb;

#define HDST(bi, k0)                                                          \
  do {                                                                        \
    GLDS(samp + (size_t)(m0 + w * 16 + srow) * 2048 + scol + (k0),            \
         &As[bi][0][w * 512 + lane * 8]);                                     \
    GLDS(Wp + (size_t)(n0l + wh * 32 + srow) * 2048 + scol + (k0),            \
         &Bs[bi][is_v ? 1 : 0][wh * 1024 + lane * 8]);                        \
    GLDS(Wp + (size_t)(n0l + wh * 32 + 16 + srow) * 2048 + scol + (k0),       \
         &Bs[bi][is_v ? 1 : 0][wh * 1024 + 512 + lane * 8]);                  \
  } while (0)

    f4 acc[4][4];
#pragma unroll
    for (int i = 0; i < 4; ++i)
#pragma unroll
      for (int j = 0; j < 4; ++j) acc[i][j] = f4{0.f, 0.f, 0.f, 0.f};
    const int koff = ks * 8;
    const int arow = wr * 64 + r, brow = wc * 64 + r;

    HDST(0, 0);
    int cur = 0;
    for (int k0 = 0; k0 < 2048; k0 += 32) {
      SB();  // B1: closes prev-iter LDS reads (WAR for cur^1)
      if (k0 + 32 < 2048) {
        HDST(cur ^ 1, k0 + 32);
        WVM(3);  // my 3 loads for THIS tile have landed
      } else {
        WVM(0);
      }
      SB();  // B2: all waves' loads landed
      bf8 af2[4], bw[4];
#pragma unroll
      for (int i = 0; i < 4; ++i)
        af2[i] = *(const bf8*)(&As[cur][0][(arow + i * 16) * 32 + koff]);
#pragma unroll
      for (int j = 0; j < 4; ++j)
        bw[j] =
            *(const bf8*)(&Bs[cur][is_v ? 1 : 0][(brow + j * 16) * 32 + koff]);
      __builtin_amdgcn_s_setprio(1);
#pragma unroll
      for (int i = 0; i < 4; ++i)
#pragma unroll
        for (int j = 0; j < 4; ++j)
          acc[i][j] = MFMA16(af2[i], bw[j], acc[i][j]);
      __builtin_amdgcn_s_setprio(0);
      cur ^= 1;
    }
#undef HDST
    const int rbase = ks * 4;
#pragma unroll
    for (int i = 0; i < 4; ++i) {
#pragma unroll
      for (int j = 0; j < 4; ++j) {
        const int nn = n0l + wc * 64 + j * 16 + r;
        const int hh = nn >> 7, dd = nn & 127;
#pragma unroll
        for (int rr = 0; rr < 4; ++rr) {
          const int m = m0 + wr * 64 + i * 16 + rbase + rr;
          const int bb = m / 576;
          const int kv = 1024 + (m - bb * 576);
          const u16 bv = f2bf1(acc[i][j][rr] + bias[nn]);
          if (!is_v) {
            kg[(((size_t)(bb * 16 + hh) * 50 + (kv >> 5)) * 16 + (dd >> 3)) *
                   256 +
               (kv & 31) * 8 + (dd & 7)] = bv;
          } else {
            vg[((size_t)(bb * 16 + hh) * 200 + (kv >> 3)) * 1024 + dd * 8 +
               (kv & 7)] = bv;
          }
        }
      }
    }
  }
}

// --------- output projection: staged x staged, counted-vmcnt pipeline -------
__global__ __launch_bounds__(256) void gemm_out_st(const u16* __restrict__ Ast2,
                                                   const u16* __restrict__ Wst,
                                                   float* __restrict__ outf) {
  __shared__ u16 As2[2][2][4096];
  __shared__ u16 Ws2[2][2][4096];
  const int tid = threadIdx.x, lane = tid & 63, w = tid >> 6;
  const int wr = w >> 1, wc = w & 1;
  const int ks = lane >> 4, r = lane & 15;
  const int mt = blockIdx.y, nt = blockIdx.x;

#define OST(bi, kt)                                                           \
  do {                                                                        \
    const size_t a0 = ((size_t)(mt * 2 + 0) * 32 + (kt)) * 4096;              \
    const size_t a1 = ((size_t)(mt * 2 + 1) * 32 + (kt)) * 4096;              \
    const size_t w0 = ((size_t)(nt * 2 + 0) * 32 + (kt)) * 4096;              \
    const size_t w1 = ((size_t)(nt * 2 + 1) * 32 + (kt)) * 4096;              \
    GLDS(Ast2 + a0 + tid * 8, &As2[bi][0][tid * 8]);                          \
    GLDS(Ast2 + a0 + 2048 + tid * 8, &As2[bi][0][2048 + tid * 8]);            \
    GLDS(Ast2 + a1 + tid * 8, &As2[bi][1][tid * 8]);                          \
    GLDS(Ast2 + a1 + 2048 + tid * 8, &As2[bi][1][2048 + tid * 8]);            \
    GLDS(Wst + w0 + tid * 8, &Ws2[bi][0][tid * 8]);                           \
    GLDS(Wst + w0 + 2048 + tid * 8, &Ws2[bi][0][2048 + tid * 8]);             \
    GLDS(Wst + w1 + tid * 8, &Ws2[bi][1][tid * 8]);                           \
    GLDS(Wst + w1 + 2048 + tid * 8, &Ws2[bi][1][2048 + tid * 8]);             \
  } while (0)

  f4 acc[4][4];
#pragma unroll
  for (int i = 0; i < 4; ++i)
#pragma unroll
    for (int j = 0; j < 4; ++j) acc[i][j] = f4{0.f, 0.f, 0.f, 0.f};

  OST(0, 0);
  int cur = 0;
  for (int kt = 0; kt < 32; ++kt) {
    SB();
    if (kt + 1 < 32) {
      OST(cur ^ 1, kt + 1);
      WVM(8);
    } else {
      WVM(0);
    }
    SB();
#pragma unroll
    for (int kc = 0; kc < 2; ++kc) {
      bf8 a_[4], b_[4];
#pragma unroll
      for (int i = 0; i < 4; ++i)
        a_[i] = *(const bf8*)(&As2[cur][wr][((i * 2 + kc) * 4 + ks) * 128 +
                                            r * 8]);
#pragma unroll
      for (int j = 0; j < 4; ++j)
        b_[j] = *(const bf8*)(&Ws2[cur][wc][((j * 2 + kc) * 4 + ks) * 128 +
                                            r * 8]);
      __builtin_amdgcn_s_setprio(1);
#pragma unroll
      for (int i = 0; i < 4; ++i)
#pragma unroll
        for (int j = 0; j < 4; ++j)
          acc[i][j] = MFMA16(a_[i], b_[j], acc[i][j]);
      __builtin_amdgcn_s_setprio(0);
    }
    cur ^= 1;
  }
#undef OST
#pragma unroll
  for (int i = 0; i < 4; ++i)
#pragma unroll
    for (int j = 0; j < 4; ++j) {
      const int n = nt * 128 + wc * 64 + j * 16 + r;
#pragma unroll
      for (int rr = 0; rr < 4; ++rr) {
        const int m = mt * 128 + wr * 64 + i * 16 + ks * 4 + rr;
        outf[(size_t)m * 2048 + n] = acc[i][j][rr];
      }
    }
}

// -------------- offset network: fused LN(512)+1x1conv + gate ----------------
__global__ __launch_bounds__(256) void lnproj_gate(
    const float* __restrict__ x1, const float* __restrict__ ln1w,
    const float* __restrict__ ln1b, const float* __restrict__ wt,
    const float* __restrict__ pooled, const float* __restrict__ piw,
    const float* __restrict__ pib, float* __restrict__ x2,
    float* __restrict__ gate) {
  __shared__ float Xs[512][68];
  __shared__ float rs[4][64], rss[4][64];
  const int bidx = blockIdx.x;
  const int t = threadIdx.x;
  if (bidx >= 72) {  // gate: blocks 72,73 -> 512 outputs
    const int idx = (bidx - 72) * 256 + t;
    const int n = idx >> 6, o = idx & 63;
    const float* pb = pooled + n * 512;
    const float* wb = piw + o * 512;
    float s = pib[o];
    for (int c = 0; c < 512; ++c) s += pb[c] * wb[c];
    gate[idx] = 1.f / (1.f + expf(-s));
    return;
  }
  const int n = bidx / 9, pc = bidx % 9;
  const int p0 = pc * 64;
  {
    const int pl = t & 63, c4 = t >> 6;
    const float* src = x1 + (size_t)n * 512 * 576 + p0 + pl;
#pragma unroll 4
    for (int j = 0; j < 128; ++j) {
      const int c = j * 4 + c4;
      Xs[c][pl] = src[(size_t)c * 576];
    }
  }
  __syncthreads();
  {
    const int pl = t & 63, q = t >> 6;
    float s = 0.f, ss = 0.f;
    for (int c = q * 128; c < q * 128 + 128; ++c) {
      const float v = Xs[c][pl];
      s += v;
      ss += v * v;
    }
    rs[q][pl] = s;
    rss[q][pl] = ss;
    __syncthreads();
    const float S = rs[0][pl] + rs[1][pl] + rs[2][pl] + rs[3][pl];
    const float SS = rss[0][pl] + rss[1][pl] + rss[2][pl] + rss[3][pl];
    const float mean = S * (1.f / 512.f);
    const float inv = rsqrtf(SS * (1.f / 512.f) - mean * mean + 1e-5f);
    for (int c = q * 128; c < q * 128 + 128; ++c)
      Xs[c][pl] = (Xs[c][pl] - mean) * inv * ln1w[c] + ln1b[c];
  }
  __syncthreads();
  {
    const int o4 = (t & 15) * 4, pl0 = (t >> 4) * 4;
    float acc[4][4] = {};
    for (int c = 0; c < 512; ++c) {
      const f4 xv = *(const f4*)(&Xs[c][pl0]);
      const f4 wv = *(const f4*)(&wt[c * 64 + o4]);
#pragma unroll
      for (int i = 0; i < 4; ++i)
#pragma unroll
        for (int j = 0; j < 4; ++j) acc[i][j] += wv[i] * xv[j];
    }
#pragma unroll
    for (int i = 0; i < 4; ++i) {
      f4 ov;
      ov[0] = acc[i][0]; ov[1] = acc[i][1];
      ov[2] = acc[i][2]; ov[3] = acc[i][3];
      *(f4*)(&x2[(size_t)(n * 64 + o4 + i) * 576 + p0 + pl0]) = ov;
    }
  }
}

// ------- fused: LN(64)+offsets+tanh positions + bilinear sample -------------
// block = (b, k): waves 0-3 compute pos for groups 0-3; then 256 thr sample.
__global__ __launch_bounds__(256) void pos_sample(
    const float* __restrict__ x2, const float* __restrict__ gate,
    const float* __restrict__ ln2w, const float* __restrict__ ln2b,
    const float* __restrict__ offw, const float* __restrict__ img,
    u16* __restrict__ samp) {
  const int bk = blockIdx.x;
  const int b = bk / K, k = bk % K;
  __shared__ int s_idx[G][4];
  __shared__ float s_w[G][4];
  const int t = threadIdx.x;
  const int g = t >> 6, lane = t & 63;
  {
    const int n = b * G + g;
    float v = x2[((size_t)n * INTER + lane) * K + k] * gate[n * INTER + lane];
    float s = v, ss = v * v;
    for (int o = 32; o; o >>= 1) {
      s += __shfl_xor(s, o);
      ss += __shfl_xor(ss, o);
    }
    const float mean = s * (1.f / INTER);
    const float var = ss * (1.f / INTER) - mean * mean;
    const float xn = (v - mean) * rsqrtf(var + 1e-5f) * ln2w[lane] + ln2b[lane];
    float ox = xn * offw[lane];
    float oy = xn * offw[INTER + lane];
    for (int o = 32; o; o >>= 1) {
      ox += __shfl_xor(ox, o);
      oy += __shfl_xor(oy, o);
    }
    if (lane == 0) {
      const int yi = k / LR, xi = k % LR;
      const float rx = (xi + 0.5f) / 23.f * 2.f - 1.f;
      const float ry = (yi + 0.5f) / 23.f * 2.f - 1.f;
      const float px = tanhf(rx + ox), py = tanhf(ry + oy);
      const float x = (px + 1.f) * 0.5f * (HR - 1);
      const float y = (py + 1.f) * 0.5f * (HR - 1);
      const float x0f = floorf(x), y0f = floorf(y);
      const float wx = x - x0f, wy = y - y0f;
      const int x0 = min(max((int)x0f, 0), HR - 1);
      const int x1 = min(x0 + 1, HR - 1);
      const int y0 = min(max((int)y0f, 0), HR - 1);
      const int y1 = min(y0 + 1, HR - 1);
      s_idx[g][0] = y0 * HR + x0;
      s_idx[g][1] = y0 * HR + x1;
      s_idx[g][2] = y1 * HR + x0;
      s_idx[g][3] = y1 * HR + x1;
      s_w[g][0] = (1.f - wx) * (1.f - wy);
      s_w[g][1] = wx * (1.f - wy);
      s_w[g][2] = (1.f - wx) * wy;
      s_w[g][3] = wx * wy;
    }
  }
  __syncthreads();
  const float* ib = img + (size_t)b * HR * HR * C;
  u16* ob = samp + ((size_t)b * K + k) * C;
  for (int ch = t; ch < C; ch += 256) {
    const int gg = ch >> 9;
    float v = s_w[gg][0] * ib[(size_t)s_idx[gg][0] * C + ch] +
              s_w[gg][1] * ib[(size_t)s_idx[gg][1] * C + ch] +
              s_w[gg][2] * ib[(size_t)s_idx[gg][2] * C + ch] +
              s_w[gg][3] * ib[(size_t)s_idx[gg][3] * C + ch];
    ob[ch] = f2bf1(v);
  }
}

// -------- KV-split MFMA flash attention, counted-vmcnt pipeline -------------
__global__ __launch_bounds__(256) void attn_part(
    const u16* __restrict__ qb, const u16* __restrict__ kg,
    const u16* __restrict__ vg, float* __restrict__ oA,
    float* __restrict__ oB, float* __restrict__ mlA,
    float* __restrict__ mlB) {
  const int i = blockIdx.x;
  const int fam = i >> 9;
  const int r9 = i & 511;
  int bh, qblk;
  if (fam == 0) {
    const int pair = r9 & 255, half = r9 >> 8;
    bh = pair & 31;
    const int q8 = pair >> 5;
    qblk = half ? (15 - q8) : q8;
  } else {
    bh = r9 & 31;
    qblk = r9 >> 5;
  }
  const int b = bh >> 4, h = bh & 15;
  const int q0 = qblk * 64;
  const int tid = threadIdx.x, lane = tid & 63, w = tid >> 6;
  const int qw = q0 + w * 16;
  const int col = lane & 15, kpart = lane >> 4, rbase = kpart * 4;
  __shared__ u16 Ks[2][4096];
  __shared__ u16 Vs[2][4096];
  __shared__ u16 Pl[4][16 * 40];
  float* oacc = fam ? oB : oA;
  float* ml = fam ? mlB : mlA;
  bf8 qf[4];
  {
    const u16* qp =
        qb + (size_t)(b * 1024 + qw + col) * 2048 + h * 128 + kpart * 8;
#pragma unroll
    for (int dc = 0; dc < 4; ++dc) qf[dc] = *(const bf8*)(qp + dc * 32);
  }
  f4 o[8];
#pragma unroll
  for (int df = 0; df < 8; ++df) o[df] = f4{0.f, 0.f, 0.f, 0.f};
  float m_r[4] = {-1e30f, -1e30f, -1e30f, -1e30f};
  float l_p[4] = {0.f, 0.f, 0.f, 0.f};
  const float scale = 0.08838834764831845f;
  const int nt = fam ? 18 : ((q0 + 64) >> 5);
  const int kvadd = fam ? 1024 : 0;
  const u16* kbh = kg + (size_t)bh * (NKV * 128);
  const u16* vbh = vg + (size_t)bh * (NKV * 128);
  u16* pw = &Pl[w][0];

#define ASTAGE(bi, kv0)                                                       \
  do {                                                                        \
    const u16* gk = kbh + (size_t)((kv0) >> 5) * 4096 + w * 1024 + lane * 8;  \
    GLDS(gk, &Ks[bi][w * 1024 + lane * 8]);                                   \
    GLDS(gk + 512, &Ks[bi][w * 1024 + 512 + lane * 8]);                       \
    const u16* gv = vbh + (size_t)((kv0) >> 3) * 1024 + w * 1024 + lane * 8;  \
    GLDS(gv, &Vs[bi][w * 1024 + lane * 8]);                                   \
    GLDS(gv + 512, &Vs[bi][w * 1024 + 512 + lane * 8]);                       \
  } while (0)

  ASTAGE(0, kvadd);
  int cur = 0;
  for (int t = 0; t < nt; ++t) {
    const int kv0 = kvadd + (t << 5);
    SB();  // B1: closes t-1 LDS reads (WAR for cur^1)
    if (t + 1 < nt) {
      ASTAGE(cur ^ 1, kvadd + ((t + 1) << 5));
      WVM(4);  // my 4 loads for tile t landed
    } else {
      WVM(0);
    }
    SB();  // B2: all waves' loads landed
    const u16* ksb = &Ks[cur][0];
    const u16* vsb = &Vs[cur][0];
    f4 s0 = {0.f, 0.f, 0.f, 0.f}, s1 = {0.f, 0.f, 0.f, 0.f};
    __builtin_amdgcn_s_setprio(1);
#pragma unroll
    for (int dc = 0; dc < 4; ++dc) {
      const int dblk = dc * 4 + kpart;
      bf8 k0f = *(const bf8*)(ksb + (dblk * 32 + col) * 8);
      bf8 k1f = *(const bf8*)(ksb + (dblk * 32 + 16 + col) * 8);
      s0 = MFMA16(qf[dc], k0f, s0);
      s1 = MFMA16(qf[dc], k1f, s1);
    }
    __builtin_amdgcn_s_setprio(0);
    float sa[4], sc[4], loc[4], p0[4], p1[4];
    bool grow = false;
    const bool need_mask = (fam == 0) && (kv0 + 31 > qw);
#pragma unroll
    for (int rr = 0; rr < 4; ++rr) {
      float a = s0[rr] * scale, c2 = s1[rr] * scale;
      if (need_mask) {
        const int qg = qw + rbase + rr;
        if (kv0 + col > qg) a = -1e30f;
        if (kv0 + 16 + col > qg) c2 = -1e30f;
      }
      sa[rr] = a; sc[rr] = c2;
      loc[rr] = fmaxf(a, c2);
      grow |= (loc[rr] > m_r[rr] + 8.f);
    }
    if (__any(grow)) {
      float fr[4];
#pragma unroll
      for (int rr = 0; rr < 4; ++rr) {
        float mx = loc[rr];
        mx = fmaxf(mx, __shfl_xor(mx, 1));
        mx = fmaxf(mx, __shfl_xor(mx, 2));
        mx = fmaxf(mx, __shfl_xor(mx, 4));
        mx = fmaxf(mx, __shfl_xor(mx, 8));
        const float mn = fmaxf(m_r[rr], mx);
        fr[rr] = __expf(m_r[rr] - mn);
        m_r[rr] = mn;
        p0[rr] = __expf(sa[rr] - mn);
        p1[rr] = __expf(sc[rr] - mn);
        l_p[rr] = l_p[rr] * fr[rr] + p0[rr] + p1[rr];
      }
#pragma unroll
      for (int df = 0; df < 8; ++df) {
        o[df][0] *= fr[0]; o[df][1] *= fr[1];
        o[df][2] *= fr[2]; o[df][3] *= fr[3];
      }
    } else {
#pragma unroll
      for (int rr = 0; rr < 4; ++rr) {
        p0[rr] = __expf(sa[rr] - m_r[rr]);
        p1[rr] = __expf(sc[rr] - m_r[rr]);
        l_p[rr] += p0[rr] + p1[rr];
      }
    }
#pragma unroll
    for (int rr = 0; rr < 4; ++rr) {
      pw[(rbase + rr) * 40 + col] = f2bf1(p0[rr]);
      pw[(rbase + rr) * 40 + 16 + col] = f2bf1(p1[rr]);
    }
    bf8 pa = *(const bf8*)(pw + col * 40 + kpart * 8);
    __builtin_amdgcn_s_setprio(1);
#pragma unroll
    for (int df = 0; df < 8; ++df) {
      bf8 vf = *(const bf8*)(vsb + (kpart * 128 + df * 16 + col) * 8);
      o[df] = MFMA16(pa, vf, o[df]);
    }
    __builtin_amdgcn_s_setprio(0);
    cur ^= 1;
  }
#undef ASTAGE
  float l_r[4];
#pragma unroll
  for (int rr = 0; rr < 4; ++rr) {
    float ps = l_p[rr];
    ps += __shfl_xor(ps, 1);
    ps += __shfl_xor(ps, 2);
    ps += __shfl_xor(ps, 4);
    ps += __shfl_xor(ps, 8);
    l_r[rr] = ps;
  }
  float* orow = oacc + (size_t)(bh * 1024 + qw + rbase) * 128 + col;
#pragma unroll
  for (int df = 0; df < 8; ++df)
#pragma unroll
    for (int rr = 0; rr < 4; ++rr)
      orow[(size_t)rr * 128 + df * 16] = o[df][rr];
  if (col == 0) {
#pragma unroll
    for (int rr = 0; rr < 4; ++rr) {
      const int row = bh * 1024 + qw + rbase + rr;
      ml[row * 2] = m_r[rr];
      ml[row * 2 + 1] = l_r[rr];
    }
  }
}

// merge partials -> aob in STAGED layout (feeds gemm_out_st directly)
__global__ __launch_bounds__(256) void attn_merge(
    const float* __restrict__ oA, const float* __restrict__ mlA,
    const float* __restrict__ oB, const float* __restrict__ mlB,
    u16* __restrict__ aob_st) {
  const int gid = blockIdx.x * 256 + threadIdx.x;
  const int row = gid >> 5;
  const int d0 = (gid & 31) * 4;
  const float mA = mlA[row * 2], lA = mlA[row * 2 + 1];
  const float mB = mlB[row * 2], lB = mlB[row * 2 + 1];
  const float m = fmaxf(mA, mB);
  const float wA = __expf(mA - m), wB = __expf(mB - m);
  const float inv = 1.f / (lA * wA + lB * wB);
  const f4 a = *(const f4*)(oA + (size_t)row * 128 + d0);
  const f4 c = *(const f4*)(oB + (size_t)row * 128 + d0);
  const int bh = row >> 10, q = row & 1023;
  const int bb = bh >> 4, h = bh & 15;
  const int mm = bb * 1024 + q;
  const int col = h * 128 + d0;
  const int mb = mm >> 6, fr = (mm >> 4) & 3, r = mm & 15;
  const int kb = col >> 6, kc = (col >> 5) & 1, ks = (col >> 3) & 3,
            j0 = col & 7;
  u16* dst = aob_st + ((size_t)(mb * 32 + kb)) * 4096 +
             (((fr * 2 + kc) * 4 + ks) * 16 + r) * 8 + j0;
  us4 ov;
  ov.x = f2bf1((a[0] * wA + c[0] * wB) * inv);
  ov.y = f2bf1((a[1] * wA + c[1] * wB) * inv);
  ov.z = f2bf1((a[2] * wA + c[2] * wB) * inv);
  ov.w = f2bf1((a[3] * wA + c[3] * wB) * inv);
  *(us4*)dst = ov;
}

// ---------------------------------------------------------------------------
extern "C" void kernel_launch(void* const* d_in, const int* in_sizes, int n_in,
                              void* d_out, int out_size, void* d_ws,
                              size_t ws_size, hipStream_t stream) {
  const float* hs = (const float*)d_in[0];
  const float* img = (const float*)d_in[1];
  const float* wq = (const float*)d_in[2];
  const float* wk = (const float*)d_in[3];
  const float* wv = (const float*)d_in[4];
  const float* wo = (const float*)d_in[5];
  const float* cdw = (const float*)d_in[6];
  const float* ln1w = (const float*)d_in[7];
  const float* ln1b = (const float*)d_in[8];
  const float* plrw = (const float*)d_in[9];
  const float* piw = (const float*)d_in[10];
  const float* pib = (const float*)d_in[11];
  const float* ln2w = (const float*)d_in[12];
  const float* ln2b = (const float*)d_in[13];
  const float* offw = (const float*)d_in[14];
  const float* khw = (const float*)d_in[15];
  const float* khb = (const float*)d_in[16];
  const float* vhw = (const float*)d_in[17];
  const float* vhb = (const float*)d_in[18];
  float* outp = (float*)d_out;

  u16* wsp = (u16*)d_ws;
  const size_t SZ = 4194304;  // 2048*2048
  u16* hs_st = wsp;
  u16* wq_st = wsp + SZ;       // reused as aob (staged) after gemm
  u16* wk_st = wsp + 2 * SZ;   // oA overlay after gemm
  u16* wv_st = wsp + 3 * SZ;   // oA overlay after gemm
  u16* wo_st = wsp + 4 * SZ;   // live until gemm_out_st
  u16* khw_bf = wsp + 5 * SZ;  // oB overlay after gemm
  u16* vhw_bf = wsp + 6 * SZ;  // oB overlay after gemm
  u16* qb_bf = wsp + 7 * SZ;
  u16* samp_bf = wsp + 8 * SZ;       // 1152*2048 row-major
  u16* kg = wsp + 8 * SZ + 2359296;  // 2*16*1600*128
  u16* vg = kg + 6553600;
  // fp32 scratch overlays kg/vg (dead before gemms)
  float* x1b = (float*)kg + 2359296;
  float* x2b = x1b + 2359296;
  float* poolb = x2b + 294912;
  float* gb = poolb + 4096;
  float* posb = (float*)(vg + 6553600);
  float* mlA = posb + 9216;
  float* mlB = mlA + 65536;
  float* wtb = mlB + 65536;
  float* oA = (float*)(wsp + 2 * SZ);
  float* oB = (float*)(wsp + 5 * SZ);
  u16* aob_st = wq_st;

  dim3 blk(256);
  // L1: conversions + plrw^T + dwconv/pool (independent work, one launch)
  f2bf_k9<<<dim3(1024, 9), blk, 0, stream>>>(
      hs, wq, wk, wv, wo, khw, vhw, plrw, cdw, hs_st, wq_st, wk_st, wv_st,
      wo_st, khw_bf, vhw_bf, wtb, x1b, poolb);
  // L2: LN(512) + 1x1 conv + gate
  lnproj_gate<<<dim3(74), blk, 0, stream>>>(x1b, ln1w, ln1b, wtb, poolb, piw,
                                            pib, x2b, gb);
  // L3: LN(64)+offsets+tanh + bilinear sample
  pos_sample<<<dim3(B * K), blk, 0, stream>>>(x2b, gb, ln2w, ln2b, offw, img,
                                              samp_bf);
  // L4: fused MFMA GEMM (QKV 256^2 8-phase + HD k/v pipelined)
  gemm_fused<<<dim3(336), dim3(512), 0, stream>>>(
      hs_st, wq_st, wk_st, wv_st, samp_bf, khw_bf, vhw_bf, khb, vhb, qb_bf,
      kg, vg);
  // L5: attention partials (counted-vmcnt pipeline)
  attn_part<<<dim3(1024), blk, 0, stream>>>(qb_bf, kg, vg, oA, oB, mlA, mlB);
  // L6: merge to staged aob
  attn_merge<<<dim3(4096), blk, 0, stream>>>(oA, mlA, oB, mlB, aob_st);
  // L7: output projection (staged x staged, pipelined)
  gemm_out_st<<<dim3(16, 16), blk, 0, stream>>>(aob_st, wo_st, outp);
}